// Round 7
// baseline (405.454 us; speedup 1.0000x reference)
//
// v5: barrier-free stripe-parallel hard rescore (atomicMin merge); rest unchanged.
#include <hip/hip_runtime.h>

// Problem constants
#define Dd 256           // embedding dim (== channel count C)
#define Kc 1024          // num codes
#define SPATIAL 16384    // 16*32*32
#define NROWS 65536      // 4 * SPATIAL
#define NELEM 16777216   // 4*256*16384
#define LOSS_OFF 16777216
#define IDX_OFF  16777217
#define PERP_OFF (16777217 + 65536)
#define MARGIN 3.5e-4f
#define HB_ROWS 16       // hard rows per resolve block
#define NSPLIT 4         // code-axis stripes (256 codes each)

typedef _Float16 f16x8 __attribute__((ext_vector_type(8)));
typedef float f32x4 __attribute__((ext_vector_type(4)));

// ============================ FAST PATH =====================================

// emb -> efp (packed MFMA-B fragment layout, f16, scaled by 1024) + eT + se.
__global__ __launch_bounds__(256) void prep2_kernel(const float* __restrict__ emb,
                                                    _Float16* __restrict__ efp,
                                                    float* __restrict__ eT,
                                                    float* __restrict__ se) {
  const int j = blockIdx.x, c = threadIdx.x;
  float v = emb[j * Dd + c];
  const int ct2 = j >> 4, l15 = j & 15;
  const int kk = c >> 5, q = (c >> 3) & 3, e = c & 7;
  efp[((size_t)(ct2 * 8 + kk) * 64 + q * 16 + l15) * 8 + e] = (_Float16)(v * 1024.0f);
  eT[c * Kc + j] = v;
  double s = (double)v * (double)v;
  #pragma unroll
  for (int off = 32; off; off >>= 1) s += __shfl_down(s, off, 64);
  __shared__ double ws4[4];
  if ((threadIdx.x & 63) == 0) ws4[threadIdx.x >> 6] = s;
  __syncthreads();
  if (threadIdx.x == 0) se[j] = (float)(ws4[0] + ws4[1] + ws4[2] + ws4[3]);
}

// Fused: z transpose->f16 + sx + MFMA scores with IN-REGISTER (min1,col,min2)
// tracking + inline easy-row resolve + ordered hard-list append.
__global__ __launch_bounds__(512, 4) void prefilter2_kernel(const float* __restrict__ z,
                                                            const _Float16* __restrict__ efp,
                                                            const float* __restrict__ se,
                                                            float* __restrict__ sx,
                                                            float* __restrict__ out_idx_f,
                                                            int* __restrict__ idx_i,
                                                            int* __restrict__ counts,
                                                            int* __restrict__ hardcnt,
                                                            int* __restrict__ hardlist,
                                                            double* __restrict__ loss_sum) {
  __shared__ _Float16 As[32 * 272];    // 17408 B transposed z tile (f16)
  __shared__ float sxp[16][32];
  __shared__ float selds[Kc];
  __shared__ float rm1w[8][32];
  __shared__ float rm2w[8][32];
  __shared__ int   rc1w[8][32];

  const int tid = threadIdx.x;
  const int n0 = blockIdx.x * 32;
  const int b = n0 >> 14, s0 = n0 & 16383;
  const float* zb = z + (size_t)b * (Dd * SPATIAL) + s0;

  // stage + transpose + sx partials (512 threads: 16 channels each)
  {
    const int r = tid & 31, cp = tid >> 5;   // cp in 0..15
    float acc = 0.0f;
    #pragma unroll
    for (int c = cp * 16; c < cp * 16 + 16; ++c) {
      const float v = zb[(size_t)c * SPATIAL + r];
      As[r * 272 + c] = (_Float16)v;
      acc = fmaf(v, v, acc);
    }
    sxp[cp][r] = acc;
  }
  selds[tid] = se[tid];
  selds[tid + 512] = se[tid + 512];
  __syncthreads();

  float sxv = 0.0f;            // per-row ||z||^2 (rows tid<32)
  if (tid < 32) {
    float s = 0.0f;
    #pragma unroll
    for (int p = 0; p < 16; ++p) s += sxp[p][tid];
    sxv = s;
    sx[n0 + tid] = s;
  }

  const int w = tid >> 6, lane = tid & 63, q = lane >> 4, l15 = lane & 15;
  const int colbase = w * 128;

  // A fragments -> registers (rows rt*16+l15, k = kk*32 + q*8)
  f16x8 Afrag[2][8];
  #pragma unroll
  for (int rt = 0; rt < 2; ++rt)
    #pragma unroll
    for (int kk = 0; kk < 8; ++kk)
      Afrag[rt][kk] = *(const f16x8*)(&As[(rt * 16 + l15) * 272 + kk * 32 + q * 8]);

  float m1[8], m2[8];
  int   c1[8];
  #pragma unroll
  for (int i = 0; i < 8; ++i) { m1[i] = 3.4e38f; m2[i] = 3.4e38f; c1[i] = 0; }

  #pragma unroll
  for (int ct = 0; ct < 8; ++ct) {
    const _Float16* bp = efp + ((size_t)((w * 8 + ct) * 8) * 64 + lane) * 8;
    f32x4 a0 = {0.f, 0.f, 0.f, 0.f}, a1 = {0.f, 0.f, 0.f, 0.f};
    #pragma unroll
    for (int kk = 0; kk < 8; ++kk) {
      const f16x8 B = *(const f16x8*)(bp + kk * 512);
      a0 = __builtin_amdgcn_mfma_f32_16x16x32_f16(Afrag[0][kk], B, a0, 0, 0, 0);
      a1 = __builtin_amdgcn_mfma_f32_16x16x32_f16(Afrag[1][kk], B, a1, 0, 0, 0);
    }
    const int col = colbase + ct * 16 + l15;
    const float sec = selds[col];
    #pragma unroll
    for (int reg = 0; reg < 4; ++reg) {
      const float sc0 = fmaf(-0.001953125f, a0[reg], sec);  // se - 2P (/1024 scale)
      const float sc1 = fmaf(-0.001953125f, a1[reg], sec);
      m2[reg] = fminf(m2[reg], fmaxf(m1[reg], sc0));
      c1[reg] = (sc0 < m1[reg]) ? col : c1[reg];
      m1[reg] = fminf(m1[reg], sc0);
      m2[4 + reg] = fminf(m2[4 + reg], fmaxf(m1[4 + reg], sc1));
      c1[4 + reg] = (sc1 < m1[4 + reg]) ? col : c1[4 + reg];
      m1[4 + reg] = fminf(m1[4 + reg], sc1);
    }
  }

  // cross-lane merge over l15 (lanes sharing q hold the same rows)
  #pragma unroll
  for (int m = 1; m <= 8; m <<= 1) {
    #pragma unroll
    for (int i = 0; i < 8; ++i) {
      const float om1 = __shfl_xor(m1[i], m, 64);
      const float om2 = __shfl_xor(m2[i], m, 64);
      const int   oc1 = __shfl_xor(c1[i], m, 64);
      m2[i] = fminf(fminf(m2[i], om2), fmaxf(m1[i], om1));
      if (om1 < m1[i]) { m1[i] = om1; c1[i] = oc1; }
    }
  }
  if (l15 == 0) {
    #pragma unroll
    for (int reg = 0; reg < 4; ++reg) {
      rm1w[w][q * 4 + reg] = m1[reg];
      rm2w[w][q * 4 + reg] = m2[reg];
      rc1w[w][q * 4 + reg] = c1[reg];
      rm1w[w][16 + q * 4 + reg] = m1[4 + reg];
      rm2w[w][16 + q * 4 + reg] = m2[4 + reg];
      rc1w[w][16 + q * 4 + reg] = c1[4 + reg];
    }
  }
  __syncthreads();

  // epilogue (first wave): cross-wave merge, easy resolve, hard append, loss
  if (tid < 64) {
    double lp = 0.0;
    int hard = 0;
    const int n = n0 + tid;
    if (tid < 32) {
      float bm1 = rm1w[0][tid], bm2 = rm2w[0][tid];
      int   bc1 = rc1w[0][tid];
      #pragma unroll
      for (int ww = 1; ww < 8; ++ww) {
        const float a1v = rm1w[ww][tid], a2v = rm2w[ww][tid];
        const int   ac = rc1w[ww][tid];
        bm2 = fminf(fminf(bm2, a2v), fmaxf(bm1, a1v));
        if (a1v < bm1) { bm1 = a1v; bc1 = ac; }
      }
      if (bm2 >= bm1 + MARGIN) {
        idx_i[n] = bc1;
        out_idx_f[n] = (float)bc1;
        atomicAdd(&counts[bc1], 1);
        lp = (double)sxv + (double)bm1;   // ||z-e||^2 = sx + (se - 2P)
      } else {
        hard = 1;
      }
    }
    const unsigned long long mask = __ballot(hard);
    const int h = __popcll(mask);
    int base = 0;
    if (tid == 0 && h) base = atomicAdd(hardcnt, h);
    base = __shfl(base, 0, 64);
    if (hard) {
      const int rank = __popcll(mask & ((1ull << tid) - 1ull));
      hardlist[base + rank] = n;
    }
    #pragma unroll
    for (int off = 32; off; off >>= 1) lp += __shfl_down(lp, off, 64);
    if (tid == 0 && lp != 0.0) atomicAdd(loss_sum, lp);
  }
}

// Barrier-free exact rescore: block = (16-row group) x (256-code stripe).
// Direct coalesced eT reads from L2 (no LDS staging, no main-loop barriers);
// FMA chain order identical to the verified v4 (ascending c per code).
// Per-row winner merged via packed u64 atomicMin (score_bits<<32 | j):
// scores ~ ||z||^2 >> 0 so float bits are monotonic; ties pick min j.
__global__ __launch_bounds__(256) void resolve_hard_kernel(const float* __restrict__ z,
                                                           const float* __restrict__ eT,
                                                           const float* __restrict__ se,
                                                           const float* __restrict__ sx,
                                                           const int* __restrict__ hardcnt,
                                                           const int* __restrict__ hardlist,
                                                           unsigned long long* __restrict__ hardres) {
  const int hc = *hardcnt;
  const int grp = blockIdx.x >> 2, stripe = blockIdx.x & 3;
  const int i0 = grp * HB_ROWS;
  if (i0 >= hc) return;
  const int tid = threadIdx.x;

  __shared__ int   sn[HB_ROWS];
  __shared__ float sxs[HB_ROWS];
  __shared__ float zx[Dd * 17];       // [c][r], stride 17 (bank-safe)
  __shared__ float ses[256];          // this stripe's se

  const int jb0 = stripe * 256;
  if (tid < HB_ROWS) {
    const int ii = i0 + tid;
    const int n = (ii < hc) ? hardlist[ii] : hardlist[i0];  // pad: dup row
    sn[tid] = n;
    sxs[tid] = sx[n];
  }
  ses[tid] = se[jb0 + tid];
  __syncthreads();

  // gather z rows (hardlist is block-ordered -> rows cluster spatially)
  {
    const int r = tid & 15, cp = tid >> 4;   // 16 channels per thread
    const int n = sn[r], b = n >> 14, s = n & 16383;
    const float* zr = z + (size_t)b * (Dd * SPATIAL) + s;
    #pragma unroll
    for (int c = cp * 16; c < cp * 16 + 16; ++c)
      zx[c * 17 + r] = zr[(size_t)c * SPATIAL];
  }
  __syncthreads();

  const int tc = tid & 15, tr = tid >> 4;    // tr = row, codes jb0+j0+4*tc+cc
  const float sxr = sxs[tr];
  float s1 = 3.4e38f;
  int   j1 = 0x7fffffff;

  for (int j0 = 0; j0 < 256; j0 += 64) {
    float acc[4] = {0.f, 0.f, 0.f, 0.f};
    const float* ecol = eT + jb0 + j0 + 4 * tc;
    #pragma unroll 8
    for (int c = 0; c < Dd; ++c) {
      const float a = zx[c * 17 + tr];
      const float4 bv = *(const float4*)(ecol + (size_t)c * Kc);
      acc[0] = fmaf(a, bv.x, acc[0]);
      acc[1] = fmaf(a, bv.y, acc[1]);
      acc[2] = fmaf(a, bv.z, acc[2]);
      acc[3] = fmaf(a, bv.w, acc[3]);
    }
    #pragma unroll
    for (int cc = 0; cc < 4; ++cc) {
      const int j = jb0 + j0 + 4 * tc + cc;
      const float t1 = sxr + ses[j0 + 4 * tc + cc];
      const float sv = t1 - 2.0f * acc[cc];
      if (sv < s1 || (sv == s1 && j < j1)) { s1 = sv; j1 = j; }
    }
  }
  // reduce across the 16 tc-lanes sharing tr (within-wave xor over 1..8)
  #pragma unroll
  for (int m = 1; m <= 8; m <<= 1) {
    const float so = __shfl_xor(s1, m, 64);
    const int   jo = __shfl_xor(j1, m, 64);
    if (so < s1 || (so == s1 && jo < j1)) { s1 = so; j1 = jo; }
  }
  if (tc == 0 && i0 + tr < hc) {
    const unsigned long long packed =
        ((unsigned long long)__float_as_uint(s1) << 32) | (unsigned int)j1;
    atomicMin(&hardres[i0 + tr], packed);
  }
}

// unpack winners: idx/counts/loss for hard rows
__global__ __launch_bounds__(256) void resolve_merge_kernel(const int* __restrict__ hardcnt,
                                                            const int* __restrict__ hardlist,
                                                            const unsigned long long* __restrict__ hardres,
                                                            float* __restrict__ out_idx_f,
                                                            int* __restrict__ idx_i,
                                                            int* __restrict__ counts,
                                                            double* __restrict__ loss_sum) {
  const int hc = *hardcnt;
  if ((int)blockIdx.x * 256 >= hc) return;
  const int tid = threadIdx.x;
  const int t = blockIdx.x * 256 + tid;
  double lp = 0.0;
  if (t < hc) {
    const unsigned long long packed = hardres[t];
    const int j = (int)(packed & 0xFFFFFFFFull);
    const float sv = __uint_as_float((unsigned int)(packed >> 32));
    const int n = hardlist[t];
    idx_i[n] = j;
    out_idx_f[n] = (float)j;
    atomicAdd(&counts[j], 1);
    lp = (double)sv;                   // sv == sx + se - 2P == ||z-e||^2
  }
  #pragma unroll
  for (int off = 32; off; off >>= 1) lp += __shfl_down(lp, off, 64);
  __shared__ double dred[4];
  if ((tid & 63) == 0) dred[tid >> 6] = lp;
  __syncthreads();
  if (tid == 0) atomicAdd(loss_sum, dred[0] + dred[1] + dred[2] + dred[3]);
}

// gather-only z_q write (out == z_q; straight-through is identity in fwd)
__global__ __launch_bounds__(256) void phase2c_kernel(const float* __restrict__ emb,
                                                      const int* __restrict__ idx_i,
                                                      float* __restrict__ out_zq) {
  __shared__ float els[64 * 257];
  __shared__ int sidx[64];
  const int tid = threadIdx.x;
  const int blk = blockIdx.x, b = blk >> 8, s0 = (blk & 255) << 6;
  if (tid < 64) sidx[tid] = idx_i[b * SPATIAL + s0 + tid];
  __syncthreads();
  {
    const int rr = tid >> 2, p = tid & 3;
    const float* ep = emb + (size_t)sidx[rr] * Dd + p * 64;
    float* dl = els + rr * 257 + p * 64;
    #pragma unroll
    for (int i = 0; i < 64; i += 4) {
      const float4 e4 = *(const float4*)(ep + i);
      dl[i] = e4.x; dl[i + 1] = e4.y; dl[i + 2] = e4.z; dl[i + 3] = e4.w;
    }
  }
  __syncthreads();
  const int s4 = tid & 15, cg = tid >> 4;
  const size_t zb = (size_t)b * (Dd * SPATIAL);
  #pragma unroll 4
  for (int c = cg; c < Dd; c += 16) {
    float4 v;
    v.x = els[(s4 * 4 + 0) * 257 + c];
    v.y = els[(s4 * 4 + 1) * 257 + c];
    v.z = els[(s4 * 4 + 2) * 257 + c];
    v.w = els[(s4 * 4 + 3) * 257 + c];
    *(float4*)(out_zq + zb + (size_t)c * SPATIAL + s0 + s4 * 4) = v;
  }
}

__global__ __launch_bounds__(256) void finalize_kernel(const int* __restrict__ counts,
                                                       const double* __restrict__ loss_sum,
                                                       float* __restrict__ out) {
  const int tid = threadIdx.x;
  double local = 0.0;
  for (int k = tid; k < Kc; k += 256) {
    const double p = (double)counts[k] / (double)NROWS;
    local += p * log(p + 1e-10);
  }
  #pragma unroll
  for (int off = 32; off; off >>= 1) local += __shfl_down(local, off, 64);
  __shared__ double dred[4];
  if ((tid & 63) == 0) dred[tid >> 6] = local;
  __syncthreads();
  if (tid == 0) {
    const double H = dred[0] + dred[1] + dred[2] + dred[3];
    out[PERP_OFF] = (float)exp(-H);
    out[LOSS_OFF] = (float)(0.25 * loss_sum[0] / (double)NELEM);
  }
}

// ===================== OLD (round-3) FALLBACK PATH ==========================

__global__ __launch_bounds__(256) void prep_kernel(const float* __restrict__ emb,
                                                   float* __restrict__ eT,
                                                   float* __restrict__ se) {
  const int j = blockIdx.x, c = threadIdx.x;
  float v = emb[j * Dd + c];
  eT[c * Kc + j] = v;
  double s = (double)v * (double)v;
  #pragma unroll
  for (int off = 32; off; off >>= 1) s += __shfl_down(s, off, 64);
  __shared__ double ws4[4];
  if ((threadIdx.x & 63) == 0) ws4[threadIdx.x >> 6] = s;
  __syncthreads();
  if (threadIdx.x == 0) se[j] = (float)(ws4[0] + ws4[1] + ws4[2] + ws4[3]);
}

__global__ __launch_bounds__(256) void sx_kernel(const float* __restrict__ z,
                                                 float* __restrict__ sx) {
  __shared__ double part[4][64];
  const int tid = threadIdx.x, r = tid & 63, cg = tid >> 6;
  const int blk = blockIdx.x, b = blk >> 8, s0 = (blk & 255) << 6;
  const float* zb = z + (size_t)b * (Dd * SPATIAL);
  double acc = 0.0;
  for (int c = cg * 64; c < cg * 64 + 64; ++c) {
    const float v = zb[(size_t)c * SPATIAL + s0 + r];
    acc += (double)v * (double)v;
  }
  part[cg][r] = acc;
  __syncthreads();
  if (tid < 64)
    sx[b * SPATIAL + s0 + tid] =
        (float)(part[0][tid] + part[1][tid] + part[2][tid] + part[3][tid]);
}

__global__ __launch_bounds__(256) void argmin_kernel(const float* __restrict__ z,
                                                     const float* __restrict__ eT,
                                                     const float* __restrict__ se,
                                                     const float* __restrict__ sx,
                                                     float* __restrict__ out_idx_f,
                                                     int* __restrict__ idx_i,
                                                     int* __restrict__ counts) {
  __shared__ float As[32 * 64];
  __shared__ float Bs[32 * 64];
  __shared__ float ses[Kc];
  __shared__ float sxs[64];
  __shared__ float redS1[64 * 16];
  __shared__ int   redI1[64 * 16];
  const int tid = threadIdx.x, tc = tid & 15, tr = tid >> 4;
  const int blk = blockIdx.x, b = blk >> 8, s0 = (blk & 255) << 6;
  const float* zb = z + (size_t)b * (Dd * SPATIAL);
  #pragma unroll
  for (int i = 0; i < 4; ++i) ses[tid + 256 * i] = se[tid + 256 * i];
  if (tid < 64) sxs[tid] = sx[b * SPATIAL + s0 + tid];
  float s1[4]; int j1[4];
  #pragma unroll
  for (int r = 0; r < 4; ++r) { s1[r] = 3.4e38f; j1[r] = 0; }
  for (int j0 = 0; j0 < Kc; j0 += 64) {
    float acc[4][4];
    #pragma unroll
    for (int rr = 0; rr < 4; ++rr)
      #pragma unroll
      for (int cc = 0; cc < 4; ++cc) acc[rr][cc] = 0.0f;
    for (int c0 = 0; c0 < Dd; c0 += 32) {
      __syncthreads();
      #pragma unroll
      for (int i = 0; i < 8; ++i) {
        const int e = i * 256 + tid, ci = e >> 6, r = e & 63;
        As[e] = zb[(size_t)(c0 + ci) * SPATIAL + s0 + r];
        Bs[e] = eT[(c0 + ci) * Kc + j0 + r];
      }
      __syncthreads();
      #pragma unroll
      for (int d = 0; d < 32; ++d) {
        const float4 av = *reinterpret_cast<const float4*>(&As[d * 64 + 4 * tr]);
        const float4 bv = *reinterpret_cast<const float4*>(&Bs[d * 64 + 4 * tc]);
        const float aa[4] = {av.x, av.y, av.z, av.w};
        const float bb[4] = {bv.x, bv.y, bv.z, bv.w};
        #pragma unroll
        for (int rr = 0; rr < 4; ++rr)
          #pragma unroll
          for (int cc = 0; cc < 4; ++cc)
            acc[rr][cc] = fmaf(aa[rr], bb[cc], acc[rr][cc]);
      }
    }
    #pragma unroll
    for (int rr = 0; rr < 4; ++rr) {
      const float sxr = sxs[4 * tr + rr];
      #pragma unroll
      for (int cc = 0; cc < 4; ++cc) {
        const int j = j0 + 4 * tc + cc;
        const float t1 = sxr + ses[j];
        const float s = t1 - 2.0f * acc[rr][cc];
        if (s < s1[rr] || (s == s1[rr] && j < j1[rr])) { s1[rr] = s; j1[rr] = j; }
      }
    }
  }
  #pragma unroll
  for (int rr = 0; rr < 4; ++rr) {
    redS1[(4 * tr + rr) * 16 + tc] = s1[rr];
    redI1[(4 * tr + rr) * 16 + tc] = j1[rr];
  }
  __syncthreads();
  if (tid < 64) {
    float bs = redS1[tid * 16];
    int bj = redI1[tid * 16];
    #pragma unroll
    for (int t = 1; t < 16; ++t) {
      const float a1 = redS1[tid * 16 + t];
      const int aj = redI1[tid * 16 + t];
      if (a1 < bs || (a1 == bs && aj < bj)) { bs = a1; bj = aj; }
    }
    const int n = b * SPATIAL + s0 + tid;
    out_idx_f[n] = (float)bj;
    idx_i[n] = bj;
    atomicAdd(&counts[bj], 1);
  }
}

__global__ __launch_bounds__(256) void phase2_kernel(const float* __restrict__ z,
                                                     const float* __restrict__ eT,
                                                     const int* __restrict__ idx_i,
                                                     float* __restrict__ out_zq,
                                                     double* __restrict__ loss_sum) {
  __shared__ int sidx[64];
  __shared__ double dred[4];
  const int tid = threadIdx.x;
  const int blk = blockIdx.x, b = blk >> 8, s0 = (blk & 255) << 6;
  if (tid < 64) sidx[tid] = idx_i[b * SPATIAL + s0 + tid];
  __syncthreads();
  const int s = tid & 63, coff = tid >> 6;
  const size_t zb = (size_t)b * (Dd * SPATIAL);
  const int myidx = sidx[s];
  double lsum = 0.0;
  for (int c = coff; c < Dd; c += 4) {
    const size_t off = zb + (size_t)c * SPATIAL + s0 + s;
    const float zv = z[off];
    const float zq = eT[c * Kc + myidx];
    out_zq[off] = zv + (zq - zv);
    const float d = zv - zq;
    lsum += (double)d * (double)d;
  }
  #pragma unroll
  for (int off = 32; off; off >>= 1) lsum += __shfl_down(lsum, off, 64);
  if ((tid & 63) == 0) dred[tid >> 6] = lsum;
  __syncthreads();
  if (tid == 0) atomicAdd(loss_sum, dred[0] + dred[1] + dred[2] + dred[3]);
}

// ================================ LAUNCH ====================================

extern "C" void kernel_launch(void* const* d_in, const int* in_sizes, int n_in,
                              void* d_out, int out_size, void* d_ws, size_t ws_size,
                              hipStream_t stream) {
  const float* z   = (const float*)d_in[0];
  const float* emb = (const float*)d_in[1];
  float* out = (float*)d_out;
  char* ws = (char*)d_ws;

  // fast-path ws layout
  const size_t OFF_SE   = 8192;
  const size_t OFF_SX   = 12288;
  const size_t OFF_EF   = 274432;
  const size_t OFF_IDX  = 1060864;
  const size_t OFF_ET   = 1585152;   // 1 MB
  const size_t OFF_RES  = 2633728;   // 512 KB u64 hard results
  const size_t OFF_HARD = 3682304;
  const size_t NEED     = 3944448;

  double* loss_sum = (double*)(ws + 0);
  int*    hardcnt  = (int*)(ws + 8);
  int*    counts   = (int*)(ws + 256);

  hipMemsetAsync(d_ws, 0, 8192, stream);  // loss_sum + hardcnt + counts

  if (ws_size >= NEED) {
    float*    se        = (float*)(ws + OFF_SE);
    float*    sx        = (float*)(ws + OFF_SX);
    _Float16* efp       = (_Float16*)(ws + OFF_EF);
    int*      idx_i     = (int*)(ws + OFF_IDX);
    float*    eT        = (float*)(ws + OFF_ET);
    unsigned long long* hardres = (unsigned long long*)(ws + OFF_RES);
    int*      hardlist  = (int*)(ws + OFF_HARD);

    hipMemsetAsync(ws + OFF_RES, 0xFF, NROWS * 8, stream);  // hardres = u64 max

    prep2_kernel<<<Kc, 256, 0, stream>>>(emb, efp, eT, se);
    prefilter2_kernel<<<2048, 512, 0, stream>>>(z, efp, se, sx,
                                                out + IDX_OFF, idx_i, counts,
                                                hardcnt, hardlist, loss_sum);
    resolve_hard_kernel<<<(NROWS / HB_ROWS) * NSPLIT, 256, 0, stream>>>(
        z, eT, se, sx, hardcnt, hardlist, hardres);
    resolve_merge_kernel<<<NROWS / 256, 256, 0, stream>>>(
        hardcnt, hardlist, hardres, out + IDX_OFF, idx_i, counts, loss_sum);
    phase2c_kernel<<<1024, 256, 0, stream>>>(emb, idx_i, out);
    finalize_kernel<<<1, 256, 0, stream>>>(counts, loss_sum, out);
  } else {
    // round-3 proven fallback
    float* eT    = (float*)(ws + 8192);
    float* se    = (float*)(ws + 8192 + 1048576);
    float* sx    = (float*)(ws + 8192 + 1048576 + 4096);
    int*   idx_i = (int*)(ws + 8192 + 1048576 + 4096 + 262144);

    prep_kernel<<<Kc, 256, 0, stream>>>(emb, eT, se);
    sx_kernel<<<1024, 256, 0, stream>>>(z, sx);
    argmin_kernel<<<1024, 256, 0, stream>>>(z, eT, se, sx, out + IDX_OFF, idx_i, counts);
    phase2_kernel<<<1024, 256, 0, stream>>>(z, eT, idx_i, out, loss_sum);
    finalize_kernel<<<1, 256, 0, stream>>>(counts, loss_sum, out);
  }
}

// Round 8
// 384.416 us; speedup vs baseline: 1.0547x; 1.0547x over previous
//
// v6: row-parallel barrier-free hard rescore (1 gather, direct eT, no merge).
#include <hip/hip_runtime.h>

// Problem constants
#define Dd 256           // embedding dim (== channel count C)
#define Kc 1024          // num codes
#define SPATIAL 16384    // 16*32*32
#define NROWS 65536      // 4 * SPATIAL
#define NELEM 16777216   // 4*256*16384
#define LOSS_OFF 16777216
#define IDX_OFF  16777217
#define PERP_OFF (16777217 + 65536)
#define MARGIN 3.5e-4f
#define RH_ROWS 4        // hard rows per resolve block (1 per wave)

typedef _Float16 f16x8 __attribute__((ext_vector_type(8)));
typedef float f32x4 __attribute__((ext_vector_type(4)));

// ============================ FAST PATH =====================================

// emb -> efp (packed MFMA-B fragment layout, f16, scaled by 1024) + eT + se.
__global__ __launch_bounds__(256) void prep2_kernel(const float* __restrict__ emb,
                                                    _Float16* __restrict__ efp,
                                                    float* __restrict__ eT,
                                                    float* __restrict__ se) {
  const int j = blockIdx.x, c = threadIdx.x;
  float v = emb[j * Dd + c];
  const int ct2 = j >> 4, l15 = j & 15;
  const int kk = c >> 5, q = (c >> 3) & 3, e = c & 7;
  efp[((size_t)(ct2 * 8 + kk) * 64 + q * 16 + l15) * 8 + e] = (_Float16)(v * 1024.0f);
  eT[c * Kc + j] = v;
  double s = (double)v * (double)v;
  #pragma unroll
  for (int off = 32; off; off >>= 1) s += __shfl_down(s, off, 64);
  __shared__ double ws4[4];
  if ((threadIdx.x & 63) == 0) ws4[threadIdx.x >> 6] = s;
  __syncthreads();
  if (threadIdx.x == 0) se[j] = (float)(ws4[0] + ws4[1] + ws4[2] + ws4[3]);
}

// Fused: z transpose->f16 + sx + MFMA scores with IN-REGISTER (min1,col,min2)
// tracking + inline easy-row resolve + ordered hard-list append.
__global__ __launch_bounds__(512, 4) void prefilter2_kernel(const float* __restrict__ z,
                                                            const _Float16* __restrict__ efp,
                                                            const float* __restrict__ se,
                                                            float* __restrict__ sx,
                                                            float* __restrict__ out_idx_f,
                                                            int* __restrict__ idx_i,
                                                            int* __restrict__ counts,
                                                            int* __restrict__ hardcnt,
                                                            int* __restrict__ hardlist,
                                                            double* __restrict__ loss_sum) {
  __shared__ _Float16 As[32 * 272];    // 17408 B transposed z tile (f16)
  __shared__ float sxp[16][32];
  __shared__ float selds[Kc];
  __shared__ float rm1w[8][32];
  __shared__ float rm2w[8][32];
  __shared__ int   rc1w[8][32];

  const int tid = threadIdx.x;
  const int n0 = blockIdx.x * 32;
  const int b = n0 >> 14, s0 = n0 & 16383;
  const float* zb = z + (size_t)b * (Dd * SPATIAL) + s0;

  // stage + transpose + sx partials (512 threads: 16 channels each)
  {
    const int r = tid & 31, cp = tid >> 5;   // cp in 0..15
    float acc = 0.0f;
    #pragma unroll
    for (int c = cp * 16; c < cp * 16 + 16; ++c) {
      const float v = zb[(size_t)c * SPATIAL + r];
      As[r * 272 + c] = (_Float16)v;
      acc = fmaf(v, v, acc);
    }
    sxp[cp][r] = acc;
  }
  selds[tid] = se[tid];
  selds[tid + 512] = se[tid + 512];
  __syncthreads();

  float sxv = 0.0f;            // per-row ||z||^2 (rows tid<32)
  if (tid < 32) {
    float s = 0.0f;
    #pragma unroll
    for (int p = 0; p < 16; ++p) s += sxp[p][tid];
    sxv = s;
    sx[n0 + tid] = s;
  }

  const int w = tid >> 6, lane = tid & 63, q = lane >> 4, l15 = lane & 15;
  const int colbase = w * 128;

  // A fragments -> registers (rows rt*16+l15, k = kk*32 + q*8)
  f16x8 Afrag[2][8];
  #pragma unroll
  for (int rt = 0; rt < 2; ++rt)
    #pragma unroll
    for (int kk = 0; kk < 8; ++kk)
      Afrag[rt][kk] = *(const f16x8*)(&As[(rt * 16 + l15) * 272 + kk * 32 + q * 8]);

  float m1[8], m2[8];
  int   c1[8];
  #pragma unroll
  for (int i = 0; i < 8; ++i) { m1[i] = 3.4e38f; m2[i] = 3.4e38f; c1[i] = 0; }

  #pragma unroll
  for (int ct = 0; ct < 8; ++ct) {
    const _Float16* bp = efp + ((size_t)((w * 8 + ct) * 8) * 64 + lane) * 8;
    f32x4 a0 = {0.f, 0.f, 0.f, 0.f}, a1 = {0.f, 0.f, 0.f, 0.f};
    #pragma unroll
    for (int kk = 0; kk < 8; ++kk) {
      const f16x8 B = *(const f16x8*)(bp + kk * 512);
      a0 = __builtin_amdgcn_mfma_f32_16x16x32_f16(Afrag[0][kk], B, a0, 0, 0, 0);
      a1 = __builtin_amdgcn_mfma_f32_16x16x32_f16(Afrag[1][kk], B, a1, 0, 0, 0);
    }
    const int col = colbase + ct * 16 + l15;
    const float sec = selds[col];
    #pragma unroll
    for (int reg = 0; reg < 4; ++reg) {
      const float sc0 = fmaf(-0.001953125f, a0[reg], sec);  // se - 2P (/1024 scale)
      const float sc1 = fmaf(-0.001953125f, a1[reg], sec);
      m2[reg] = fminf(m2[reg], fmaxf(m1[reg], sc0));
      c1[reg] = (sc0 < m1[reg]) ? col : c1[reg];
      m1[reg] = fminf(m1[reg], sc0);
      m2[4 + reg] = fminf(m2[4 + reg], fmaxf(m1[4 + reg], sc1));
      c1[4 + reg] = (sc1 < m1[4 + reg]) ? col : c1[4 + reg];
      m1[4 + reg] = fminf(m1[4 + reg], sc1);
    }
  }

  // cross-lane merge over l15 (lanes sharing q hold the same rows)
  #pragma unroll
  for (int m = 1; m <= 8; m <<= 1) {
    #pragma unroll
    for (int i = 0; i < 8; ++i) {
      const float om1 = __shfl_xor(m1[i], m, 64);
      const float om2 = __shfl_xor(m2[i], m, 64);
      const int   oc1 = __shfl_xor(c1[i], m, 64);
      m2[i] = fminf(fminf(m2[i], om2), fmaxf(m1[i], om1));
      if (om1 < m1[i]) { m1[i] = om1; c1[i] = oc1; }
    }
  }
  if (l15 == 0) {
    #pragma unroll
    for (int reg = 0; reg < 4; ++reg) {
      rm1w[w][q * 4 + reg] = m1[reg];
      rm2w[w][q * 4 + reg] = m2[reg];
      rc1w[w][q * 4 + reg] = c1[reg];
      rm1w[w][16 + q * 4 + reg] = m1[4 + reg];
      rm2w[w][16 + q * 4 + reg] = m2[4 + reg];
      rc1w[w][16 + q * 4 + reg] = c1[4 + reg];
    }
  }
  __syncthreads();

  // epilogue (first wave): cross-wave merge, easy resolve, hard append, loss
  if (tid < 64) {
    double lp = 0.0;
    int hard = 0;
    const int n = n0 + tid;
    if (tid < 32) {
      float bm1 = rm1w[0][tid], bm2 = rm2w[0][tid];
      int   bc1 = rc1w[0][tid];
      #pragma unroll
      for (int ww = 1; ww < 8; ++ww) {
        const float a1v = rm1w[ww][tid], a2v = rm2w[ww][tid];
        const int   ac = rc1w[ww][tid];
        bm2 = fminf(fminf(bm2, a2v), fmaxf(bm1, a1v));
        if (a1v < bm1) { bm1 = a1v; bc1 = ac; }
      }
      if (bm2 >= bm1 + MARGIN) {
        idx_i[n] = bc1;
        out_idx_f[n] = (float)bc1;
        atomicAdd(&counts[bc1], 1);
        lp = (double)sxv + (double)bm1;   // ||z-e||^2 = sx + (se - 2P)
      } else {
        hard = 1;
      }
    }
    const unsigned long long mask = __ballot(hard);
    const int h = __popcll(mask);
    int base = 0;
    if (tid == 0 && h) base = atomicAdd(hardcnt, h);
    base = __shfl(base, 0, 64);
    if (hard) {
      const int rank = __popcll(mask & ((1ull << tid) - 1ull));
      hardlist[base + rank] = n;
    }
    #pragma unroll
    for (int off = 32; off; off >>= 1) lp += __shfl_down(lp, off, 64);
    if (tid == 0 && lp != 0.0) atomicAdd(loss_sum, lp);
  }
}

// Row-parallel exact rescore: block = 4 hard rows (1 per wave) x all 1024
// codes. z gathered ONCE per row; eT read directly (coalesced 1KB/wave/c,
// L1-shared across the 4 waves). No main-loop barriers, no cross-wave merge:
// each wave owns its row and writes the result directly. FMA chain ascending
// c per code — bit-identical to the verified v4 scores.
__global__ __launch_bounds__(256) void resolve_hard_kernel(const float* __restrict__ z,
                                                           const float* __restrict__ eT,
                                                           const float* __restrict__ se,
                                                           const float* __restrict__ sx,
                                                           const int* __restrict__ hardcnt,
                                                           const int* __restrict__ hardlist,
                                                           float* __restrict__ out_idx_f,
                                                           int* __restrict__ idx_i,
                                                           int* __restrict__ counts,
                                                           double* __restrict__ loss_sum) {
  const int hc = *hardcnt;
  const int i0 = blockIdx.x * RH_ROWS;
  if (i0 >= hc) return;
  const int tid = threadIdx.x;

  __shared__ int   sn[RH_ROWS];
  __shared__ float sxs[RH_ROWS];
  __shared__ float zx[RH_ROWS][260];  // [r][c]
  __shared__ float ses[Kc];
  __shared__ double dred[RH_ROWS];

  if (tid < RH_ROWS) {
    const int ii = i0 + tid;
    const int n = (ii < hc) ? hardlist[ii] : hardlist[i0];  // pad: dup row
    sn[tid] = n;
    sxs[tid] = sx[n];
  }
  #pragma unroll
  for (int i = 0; i < 4; ++i) ses[tid + 256 * i] = se[tid + 256 * i];
  __syncthreads();

  // gather z rows once (hardlist is block-ordered -> spatial clustering)
  {
    const int r = tid & 3, cp = tid >> 2;    // 4 channels per thread
    const int n = sn[r], b = n >> 14, s = n & 16383;
    const float* zr = z + (size_t)b * (Dd * SPATIAL) + s;
    #pragma unroll
    for (int c = cp * 4; c < cp * 4 + 4; ++c)
      zx[r][c] = zr[(size_t)c * SPATIAL];
  }
  __syncthreads();

  const int tr = tid >> 6, tc = tid & 63;    // wave tr owns row tr
  const float sxr = sxs[tr];
  float s1 = 3.4e38f;
  int   j1 = 0x7fffffff;

  for (int j0 = 0; j0 < Kc; j0 += 256) {
    float acc[4] = {0.f, 0.f, 0.f, 0.f};
    const float* ecol = eT + j0 + 4 * tc;
    #pragma unroll 8
    for (int c = 0; c < Dd; ++c) {
      const float a = zx[tr][c];             // wave-uniform broadcast
      const float4 bv = *(const float4*)(ecol + (size_t)c * Kc);
      acc[0] = fmaf(a, bv.x, acc[0]);
      acc[1] = fmaf(a, bv.y, acc[1]);
      acc[2] = fmaf(a, bv.z, acc[2]);
      acc[3] = fmaf(a, bv.w, acc[3]);
    }
    #pragma unroll
    for (int cc = 0; cc < 4; ++cc) {
      const int j = j0 + 4 * tc + cc;
      const float t1 = sxr + ses[j];
      const float sv = t1 - 2.0f * acc[cc];
      if (sv < s1 || (sv == s1 && j < j1)) { s1 = sv; j1 = j; }
    }
  }
  // full-wave (min, argmin) reduce with min-j tie-break
  #pragma unroll
  for (int m = 1; m <= 32; m <<= 1) {
    const float so = __shfl_xor(s1, m, 64);
    const int   jo = __shfl_xor(j1, m, 64);
    if (so < s1 || (so == s1 && jo < j1)) { s1 = so; j1 = jo; }
  }
  double lp = 0.0;
  if (tc == 0 && i0 + tr < hc) {
    const int n = sn[tr];
    idx_i[n] = j1;
    out_idx_f[n] = (float)j1;
    atomicAdd(&counts[j1], 1);
    lp = (double)s1;                   // s1 == sx + se - 2P == ||z-e||^2
  }
  if (tc == 0) dred[tr] = lp;
  __syncthreads();
  if (tid == 0) {
    const double t = dred[0] + dred[1] + dred[2] + dred[3];
    if (t != 0.0) atomicAdd(loss_sum, t);
  }
}

// gather-only z_q write (out == z_q; straight-through is identity in fwd)
__global__ __launch_bounds__(256) void phase2c_kernel(const float* __restrict__ emb,
                                                      const int* __restrict__ idx_i,
                                                      float* __restrict__ out_zq) {
  __shared__ float els[64 * 257];
  __shared__ int sidx[64];
  const int tid = threadIdx.x;
  const int blk = blockIdx.x, b = blk >> 8, s0 = (blk & 255) << 6;
  if (tid < 64) sidx[tid] = idx_i[b * SPATIAL + s0 + tid];
  __syncthreads();
  {
    const int rr = tid >> 2, p = tid & 3;
    const float* ep = emb + (size_t)sidx[rr] * Dd + p * 64;
    float* dl = els + rr * 257 + p * 64;
    #pragma unroll
    for (int i = 0; i < 64; i += 4) {
      const float4 e4 = *(const float4*)(ep + i);
      dl[i] = e4.x; dl[i + 1] = e4.y; dl[i + 2] = e4.z; dl[i + 3] = e4.w;
    }
  }
  __syncthreads();
  const int s4 = tid & 15, cg = tid >> 4;
  const size_t zb = (size_t)b * (Dd * SPATIAL);
  #pragma unroll 4
  for (int c = cg; c < Dd; c += 16) {
    float4 v;
    v.x = els[(s4 * 4 + 0) * 257 + c];
    v.y = els[(s4 * 4 + 1) * 257 + c];
    v.z = els[(s4 * 4 + 2) * 257 + c];
    v.w = els[(s4 * 4 + 3) * 257 + c];
    *(float4*)(out_zq + zb + (size_t)c * SPATIAL + s0 + s4 * 4) = v;
  }
}

__global__ __launch_bounds__(256) void finalize_kernel(const int* __restrict__ counts,
                                                       const double* __restrict__ loss_sum,
                                                       float* __restrict__ out) {
  const int tid = threadIdx.x;
  double local = 0.0;
  for (int k = tid; k < Kc; k += 256) {
    const double p = (double)counts[k] / (double)NROWS;
    local += p * log(p + 1e-10);
  }
  #pragma unroll
  for (int off = 32; off; off >>= 1) local += __shfl_down(local, off, 64);
  __shared__ double dred[4];
  if ((tid & 63) == 0) dred[tid >> 6] = local;
  __syncthreads();
  if (tid == 0) {
    const double H = dred[0] + dred[1] + dred[2] + dred[3];
    out[PERP_OFF] = (float)exp(-H);
    out[LOSS_OFF] = (float)(0.25 * loss_sum[0] / (double)NELEM);
  }
}

// ===================== OLD (round-3) FALLBACK PATH ==========================

__global__ __launch_bounds__(256) void prep_kernel(const float* __restrict__ emb,
                                                   float* __restrict__ eT,
                                                   float* __restrict__ se) {
  const int j = blockIdx.x, c = threadIdx.x;
  float v = emb[j * Dd + c];
  eT[c * Kc + j] = v;
  double s = (double)v * (double)v;
  #pragma unroll
  for (int off = 32; off; off >>= 1) s += __shfl_down(s, off, 64);
  __shared__ double ws4[4];
  if ((threadIdx.x & 63) == 0) ws4[threadIdx.x >> 6] = s;
  __syncthreads();
  if (threadIdx.x == 0) se[j] = (float)(ws4[0] + ws4[1] + ws4[2] + ws4[3]);
}

__global__ __launch_bounds__(256) void sx_kernel(const float* __restrict__ z,
                                                 float* __restrict__ sx) {
  __shared__ double part[4][64];
  const int tid = threadIdx.x, r = tid & 63, cg = tid >> 6;
  const int blk = blockIdx.x, b = blk >> 8, s0 = (blk & 255) << 6;
  const float* zb = z + (size_t)b * (Dd * SPATIAL);
  double acc = 0.0;
  for (int c = cg * 64; c < cg * 64 + 64; ++c) {
    const float v = zb[(size_t)c * SPATIAL + s0 + r];
    acc += (double)v * (double)v;
  }
  part[cg][r] = acc;
  __syncthreads();
  if (tid < 64)
    sx[b * SPATIAL + s0 + tid] =
        (float)(part[0][tid] + part[1][tid] + part[2][tid] + part[3][tid]);
}

__global__ __launch_bounds__(256) void argmin_kernel(const float* __restrict__ z,
                                                     const float* __restrict__ eT,
                                                     const float* __restrict__ se,
                                                     const float* __restrict__ sx,
                                                     float* __restrict__ out_idx_f,
                                                     int* __restrict__ idx_i,
                                                     int* __restrict__ counts) {
  __shared__ float As[32 * 64];
  __shared__ float Bs[32 * 64];
  __shared__ float ses[Kc];
  __shared__ float sxs[64];
  __shared__ float redS1[64 * 16];
  __shared__ int   redI1[64 * 16];
  const int tid = threadIdx.x, tc = tid & 15, tr = tid >> 4;
  const int blk = blockIdx.x, b = blk >> 8, s0 = (blk & 255) << 6;
  const float* zb = z + (size_t)b * (Dd * SPATIAL);
  #pragma unroll
  for (int i = 0; i < 4; ++i) ses[tid + 256 * i] = se[tid + 256 * i];
  if (tid < 64) sxs[tid] = sx[b * SPATIAL + s0 + tid];
  float s1[4]; int j1[4];
  #pragma unroll
  for (int r = 0; r < 4; ++r) { s1[r] = 3.4e38f; j1[r] = 0; }
  for (int j0 = 0; j0 < Kc; j0 += 64) {
    float acc[4][4];
    #pragma unroll
    for (int rr = 0; rr < 4; ++rr)
      #pragma unroll
      for (int cc = 0; cc < 4; ++cc) acc[rr][cc] = 0.0f;
    for (int c0 = 0; c0 < Dd; c0 += 32) {
      __syncthreads();
      #pragma unroll
      for (int i = 0; i < 8; ++i) {
        const int e = i * 256 + tid, ci = e >> 6, r = e & 63;
        As[e] = zb[(size_t)(c0 + ci) * SPATIAL + s0 + r];
        Bs[e] = eT[(c0 + ci) * Kc + j0 + r];
      }
      __syncthreads();
      #pragma unroll
      for (int d = 0; d < 32; ++d) {
        const float4 av = *reinterpret_cast<const float4*>(&As[d * 64 + 4 * tr]);
        const float4 bv = *reinterpret_cast<const float4*>(&Bs[d * 64 + 4 * tc]);
        const float aa[4] = {av.x, av.y, av.z, av.w};
        const float bb[4] = {bv.x, bv.y, bv.z, bv.w};
        #pragma unroll
        for (int rr = 0; rr < 4; ++rr)
          #pragma unroll
          for (int cc = 0; cc < 4; ++cc)
            acc[rr][cc] = fmaf(aa[rr], bb[cc], acc[rr][cc]);
      }
    }
    #pragma unroll
    for (int rr = 0; rr < 4; ++rr) {
      const float sxr = sxs[4 * tr + rr];
      #pragma unroll
      for (int cc = 0; cc < 4; ++cc) {
        const int j = j0 + 4 * tc + cc;
        const float t1 = sxr + ses[j];
        const float s = t1 - 2.0f * acc[rr][cc];
        if (s < s1[rr] || (s == s1[rr] && j < j1[rr])) { s1[rr] = s; j1[rr] = j; }
      }
    }
  }
  #pragma unroll
  for (int rr = 0; rr < 4; ++rr) {
    redS1[(4 * tr + rr) * 16 + tc] = s1[rr];
    redI1[(4 * tr + rr) * 16 + tc] = j1[rr];
  }
  __syncthreads();
  if (tid < 64) {
    float bs = redS1[tid * 16];
    int bj = redI1[tid * 16];
    #pragma unroll
    for (int t = 1; t < 16; ++t) {
      const float a1 = redS1[tid * 16 + t];
      const int aj = redI1[tid * 16 + t];
      if (a1 < bs || (a1 == bs && aj < bj)) { bs = a1; bj = aj; }
    }
    const int n = b * SPATIAL + s0 + tid;
    out_idx_f[n] = (float)bj;
    idx_i[n] = bj;
    atomicAdd(&counts[bj], 1);
  }
}

__global__ __launch_bounds__(256) void phase2_kernel(const float* __restrict__ z,
                                                     const float* __restrict__ eT,
                                                     const int* __restrict__ idx_i,
                                                     float* __restrict__ out_zq,
                                                     double* __restrict__ loss_sum) {
  __shared__ int sidx[64];
  __shared__ double dred[4];
  const int tid = threadIdx.x;
  const int blk = blockIdx.x, b = blk >> 8, s0 = (blk & 255) << 6;
  if (tid < 64) sidx[tid] = idx_i[b * SPATIAL + s0 + tid];
  __syncthreads();
  const int s = tid & 63, coff = tid >> 6;
  const size_t zb = (size_t)b * (Dd * SPATIAL);
  const int myidx = sidx[s];
  double lsum = 0.0;
  for (int c = coff; c < Dd; c += 4) {
    const size_t off = zb + (size_t)c * SPATIAL + s0 + s;
    const float zv = z[off];
    const float zq = eT[c * Kc + myidx];
    out_zq[off] = zv + (zq - zv);
    const float d = zv - zq;
    lsum += (double)d * (double)d;
  }
  #pragma unroll
  for (int off = 32; off; off >>= 1) lsum += __shfl_down(lsum, off, 64);
  if ((tid & 63) == 0) dred[tid >> 6] = lsum;
  __syncthreads();
  if (tid == 0) atomicAdd(loss_sum, dred[0] + dred[1] + dred[2] + dred[3]);
}

// ================================ LAUNCH ====================================

extern "C" void kernel_launch(void* const* d_in, const int* in_sizes, int n_in,
                              void* d_out, int out_size, void* d_ws, size_t ws_size,
                              hipStream_t stream) {
  const float* z   = (const float*)d_in[0];
  const float* emb = (const float*)d_in[1];
  float* out = (float*)d_out;
  char* ws = (char*)d_ws;

  // fast-path ws layout
  const size_t OFF_SE   = 8192;
  const size_t OFF_SX   = 12288;
  const size_t OFF_EF   = 274432;
  const size_t OFF_IDX  = 1060864;
  const size_t OFF_ET   = 1585152;   // 1 MB
  const size_t OFF_HARD = 3682304;
  const size_t NEED     = 3944448;

  double* loss_sum = (double*)(ws + 0);
  int*    hardcnt  = (int*)(ws + 8);
  int*    counts   = (int*)(ws + 256);

  hipMemsetAsync(d_ws, 0, 8192, stream);  // loss_sum + hardcnt + counts

  if (ws_size >= NEED) {
    float*    se        = (float*)(ws + OFF_SE);
    float*    sx        = (float*)(ws + OFF_SX);
    _Float16* efp       = (_Float16*)(ws + OFF_EF);
    int*      idx_i     = (int*)(ws + OFF_IDX);
    float*    eT        = (float*)(ws + OFF_ET);
    int*      hardlist  = (int*)(ws + OFF_HARD);

    prep2_kernel<<<Kc, 256, 0, stream>>>(emb, efp, eT, se);
    prefilter2_kernel<<<2048, 512, 0, stream>>>(z, efp, se, sx,
                                                out + IDX_OFF, idx_i, counts,
                                                hardcnt, hardlist, loss_sum);
    resolve_hard_kernel<<<NROWS / RH_ROWS, 256, 0, stream>>>(
        z, eT, se, sx, hardcnt, hardlist, out + IDX_OFF, idx_i, counts, loss_sum);
    phase2c_kernel<<<1024, 256, 0, stream>>>(emb, idx_i, out);
    finalize_kernel<<<1, 256, 0, stream>>>(counts, loss_sum, out);
  } else {
    // round-3 proven fallback
    float* eT    = (float*)(ws + 8192);
    float* se    = (float*)(ws + 8192 + 1048576);
    float* sx    = (float*)(ws + 8192 + 1048576 + 4096);
    int*   idx_i = (int*)(ws + 8192 + 1048576 + 4096 + 262144);

    prep_kernel<<<Kc, 256, 0, stream>>>(emb, eT, se);
    sx_kernel<<<1024, 256, 0, stream>>>(z, sx);
    argmin_kernel<<<1024, 256, 0, stream>>>(z, eT, se, sx, out + IDX_OFF, idx_i, counts);
    phase2_kernel<<<1024, 256, 0, stream>>>(z, eT, idx_i, out, loss_sum);
    finalize_kernel<<<1, 256, 0, stream>>>(counts, loss_sum, out);
  }
}

// Round 10
// 290.046 us; speedup vs baseline: 1.3979x; 1.3254x over previous
//
// v7b: identical semantics to round-8 v7; hash-perturbed resubmit after a
// broker-side double container failure (same protocol as rounds 3-5).
#include <hip/hip_runtime.h>

// Problem constants
#define Dd 256           // embedding dim (== channel count C)
#define Kc 1024          // num codes
#define SPATIAL 16384    // 16*32*32
#define NROWS 65536      // 4 * SPATIAL
#define NELEM 16777216   // 4*256*16384
#define LOSS_OFF 16777216
#define IDX_OFF  16777217
#define PERP_OFF (16777217 + 65536)
#define MARGIN 3.5e-4f
#define RH_ROWS 8        // hard rows per resolve block

typedef _Float16 f16x8 __attribute__((ext_vector_type(8)));
typedef float f32x4 __attribute__((ext_vector_type(4)));

// ============================ FAST PATH =====================================

// emb -> efp (packed MFMA-B fragment layout, f16, scaled by 1024) + eT + se.
__global__ __launch_bounds__(256) void prep2_kernel(const float* __restrict__ emb,
                                                    _Float16* __restrict__ efp,
                                                    float* __restrict__ eT,
                                                    float* __restrict__ se) {
  const int j = blockIdx.x, c = threadIdx.x;
  float v = emb[j * Dd + c];
  const int ct2 = j >> 4, l15 = j & 15;
  const int kk = c >> 5, q = (c >> 3) & 3, e = c & 7;
  efp[((size_t)(ct2 * 8 + kk) * 64 + q * 16 + l15) * 8 + e] = (_Float16)(v * 1024.0f);
  eT[c * Kc + j] = v;
  double s = (double)v * (double)v;
  #pragma unroll
  for (int off = 32; off; off >>= 1) s += __shfl_down(s, off, 64);
  __shared__ double ws4[4];
  if ((threadIdx.x & 63) == 0) ws4[threadIdx.x >> 6] = s;
  __syncthreads();
  if (threadIdx.x == 0) se[j] = (float)(ws4[0] + ws4[1] + ws4[2] + ws4[3]);
}

// Fused: z transpose->f16 + sx + MFMA scores with IN-REGISTER (min1,col,min2)
// tracking + inline easy-row resolve + ordered hard-list append.
__global__ __launch_bounds__(512, 4) void prefilter2_kernel(const float* __restrict__ z,
                                                            const _Float16* __restrict__ efp,
                                                            const float* __restrict__ se,
                                                            float* __restrict__ sx,
                                                            float* __restrict__ out_idx_f,
                                                            int* __restrict__ idx_i,
                                                            int* __restrict__ counts,
                                                            int* __restrict__ hardcnt,
                                                            int* __restrict__ hardlist,
                                                            double* __restrict__ loss_sum) {
  __shared__ _Float16 As[32 * 272];    // 17408 B transposed z tile (f16)
  __shared__ float sxp[16][32];
  __shared__ float selds[Kc];
  __shared__ float rm1w[8][32];
  __shared__ float rm2w[8][32];
  __shared__ int   rc1w[8][32];

  const int tid = threadIdx.x;
  const int n0 = blockIdx.x * 32;
  const int b = n0 >> 14, s0 = n0 & 16383;
  const float* zb = z + (size_t)b * (Dd * SPATIAL) + s0;

  // stage + transpose + sx partials (512 threads: 16 channels each)
  {
    const int r = tid & 31, cp = tid >> 5;   // cp in 0..15
    float acc = 0.0f;
    #pragma unroll
    for (int c = cp * 16; c < cp * 16 + 16; ++c) {
      const float v = zb[(size_t)c * SPATIAL + r];
      As[r * 272 + c] = (_Float16)v;
      acc = fmaf(v, v, acc);
    }
    sxp[cp][r] = acc;
  }
  selds[tid] = se[tid];
  selds[tid + 512] = se[tid + 512];
  __syncthreads();

  float sxv = 0.0f;            // per-row ||z||^2 (rows tid<32)
  if (tid < 32) {
    float s = 0.0f;
    #pragma unroll
    for (int p = 0; p < 16; ++p) s += sxp[p][tid];
    sxv = s;
    sx[n0 + tid] = s;
  }

  const int w = tid >> 6, lane = tid & 63, q = lane >> 4, l15 = lane & 15;
  const int colbase = w * 128;

  // A fragments -> registers (rows rt*16+l15, k = kk*32 + q*8)
  f16x8 Afrag[2][8];
  #pragma unroll
  for (int rt = 0; rt < 2; ++rt)
    #pragma unroll
    for (int kk = 0; kk < 8; ++kk)
      Afrag[rt][kk] = *(const f16x8*)(&As[(rt * 16 + l15) * 272 + kk * 32 + q * 8]);

  float m1[8], m2[8];
  int   c1[8];
  #pragma unroll
  for (int i = 0; i < 8; ++i) { m1[i] = 3.4e38f; m2[i] = 3.4e38f; c1[i] = 0; }

  #pragma unroll
  for (int ct = 0; ct < 8; ++ct) {
    const _Float16* bp = efp + ((size_t)((w * 8 + ct) * 8) * 64 + lane) * 8;
    f32x4 a0 = {0.f, 0.f, 0.f, 0.f}, a1 = {0.f, 0.f, 0.f, 0.f};
    #pragma unroll
    for (int kk = 0; kk < 8; ++kk) {
      const f16x8 B = *(const f16x8*)(bp + kk * 512);
      a0 = __builtin_amdgcn_mfma_f32_16x16x32_f16(Afrag[0][kk], B, a0, 0, 0, 0);
      a1 = __builtin_amdgcn_mfma_f32_16x16x32_f16(Afrag[1][kk], B, a1, 0, 0, 0);
    }
    const int col = colbase + ct * 16 + l15;
    const float sec = selds[col];
    #pragma unroll
    for (int reg = 0; reg < 4; ++reg) {
      const float sc0 = fmaf(-0.001953125f, a0[reg], sec);  // se - 2P (/1024 scale)
      const float sc1 = fmaf(-0.001953125f, a1[reg], sec);
      m2[reg] = fminf(m2[reg], fmaxf(m1[reg], sc0));
      c1[reg] = (sc0 < m1[reg]) ? col : c1[reg];
      m1[reg] = fminf(m1[reg], sc0);
      m2[4 + reg] = fminf(m2[4 + reg], fmaxf(m1[4 + reg], sc1));
      c1[4 + reg] = (sc1 < m1[4 + reg]) ? col : c1[4 + reg];
      m1[4 + reg] = fminf(m1[4 + reg], sc1);
    }
  }

  // cross-lane merge over l15 (lanes sharing q hold the same rows)
  #pragma unroll
  for (int m = 1; m <= 8; m <<= 1) {
    #pragma unroll
    for (int i = 0; i < 8; ++i) {
      const float om1 = __shfl_xor(m1[i], m, 64);
      const float om2 = __shfl_xor(m2[i], m, 64);
      const int   oc1 = __shfl_xor(c1[i], m, 64);
      m2[i] = fminf(fminf(m2[i], om2), fmaxf(m1[i], om1));
      if (om1 < m1[i]) { m1[i] = om1; c1[i] = oc1; }
    }
  }
  if (l15 == 0) {
    #pragma unroll
    for (int reg = 0; reg < 4; ++reg) {
      rm1w[w][q * 4 + reg] = m1[reg];
      rm2w[w][q * 4 + reg] = m2[reg];
      rc1w[w][q * 4 + reg] = c1[reg];
      rm1w[w][16 + q * 4 + reg] = m1[4 + reg];
      rm2w[w][16 + q * 4 + reg] = m2[4 + reg];
      rc1w[w][16 + q * 4 + reg] = c1[4 + reg];
    }
  }
  __syncthreads();

  // epilogue (first wave): cross-wave merge, easy resolve, hard append, loss
  if (tid < 64) {
    double lp = 0.0;
    int hard = 0;
    const int n = n0 + tid;
    if (tid < 32) {
      float bm1 = rm1w[0][tid], bm2 = rm2w[0][tid];
      int   bc1 = rc1w[0][tid];
      #pragma unroll
      for (int ww = 1; ww < 8; ++ww) {
        const float a1v = rm1w[ww][tid], a2v = rm2w[ww][tid];
        const int   ac = rc1w[ww][tid];
        bm2 = fminf(fminf(bm2, a2v), fmaxf(bm1, a1v));
        if (a1v < bm1) { bm1 = a1v; bc1 = ac; }
      }
      if (bm2 >= bm1 + MARGIN) {
        idx_i[n] = bc1;
        out_idx_f[n] = (float)bc1;
        atomicAdd(&counts[bc1], 1);
        lp = (double)sxv + (double)bm1;   // ||z-e||^2 = sx + (se - 2P)
      } else {
        hard = 1;
      }
    }
    const unsigned long long mask = __ballot(hard);
    const int h = __popcll(mask);
    int base = 0;
    if (tid == 0 && h) base = atomicAdd(hardcnt, h);
    base = __shfl(base, 0, 64);
    if (hard) {
      const int rank = __popcll(mask & ((1ull << tid) - 1ull));
      hardlist[base + rank] = n;
    }
    #pragma unroll
    for (int off = 32; off; off >>= 1) lp += __shfl_down(lp, off, 64);
    if (tid == 0 && lp != 0.0) atomicAdd(loss_sum, lp);
  }
}

// Exact rescore, co-tiled: block = 8 hard rows x 1024 codes; wave w owns code
// quarter [256w, 256w+256) for ALL 8 rows -> 32 FMAs per eT float4 load, 32
// independent chains/lane. z staged once as zxT[c][row] (16B-aligned rows,
// broadcast ds_read_b128 in main loop). Per-code FMA chain ascending c —
// bit-identical scores to verified v4/v6; min-j tie-break at every level.
__global__ __launch_bounds__(256) void resolve_hard_kernel(const float* __restrict__ z,
                                                           const float* __restrict__ eT,
                                                           const float* __restrict__ se,
                                                           const float* __restrict__ sx,
                                                           const int* __restrict__ hardcnt,
                                                           const int* __restrict__ hardlist,
                                                           float* __restrict__ out_idx_f,
                                                           int* __restrict__ idx_i,
                                                           int* __restrict__ counts,
                                                           double* __restrict__ loss_sum) {
  const int hc = *hardcnt;
  const int i0 = blockIdx.x * RH_ROWS;
  if (i0 >= hc) return;
  const int tid = threadIdx.x;

  __shared__ int   sn[RH_ROWS];
  __shared__ float sxs[RH_ROWS];
  __shared__ __align__(16) float zxT[Dd][12];   // [c][row], row-quad 16B aligned
  __shared__ float redS[RH_ROWS][4];
  __shared__ int   redI[RH_ROWS][4];
  __shared__ double dred[RH_ROWS];

  if (tid < RH_ROWS) {
    const int ii = i0 + tid;
    const int n = (ii < hc) ? hardlist[ii] : hardlist[i0];  // pad: dup row
    sn[tid] = n;
    sxs[tid] = sx[n];
  }
  __syncthreads();

  // gather z rows once: row r by 32 threads, 8 channels each
  {
    const int r = tid >> 5, cs = tid & 31;
    const int n = sn[r], b = n >> 14, s = n & 16383;
    const float* zr = z + (size_t)b * (Dd * SPATIAL) + s;
    #pragma unroll
    for (int k = 0; k < 8; ++k)
      zxT[cs + 32 * k][r] = zr[(size_t)(cs + 32 * k) * SPATIAL];
  }
  __syncthreads();

  const int w = tid >> 6, lane = tid & 63;
  const int jbase = w * 256 + 4 * lane;        // this lane's 4 codes
  const float4 se4v = *(const float4*)(se + jbase);
  const float ses4[4] = {se4v.x, se4v.y, se4v.z, se4v.w};

  float acc[RH_ROWS][4];
  #pragma unroll
  for (int r = 0; r < RH_ROWS; ++r)
    #pragma unroll
    for (int cc = 0; cc < 4; ++cc) acc[r][cc] = 0.f;

  const float* ecol = eT + jbase;
  #pragma unroll 4
  for (int c = 0; c < Dd; ++c) {
    const float4 bv = *(const float4*)(ecol + (size_t)c * Kc);
    const float4 a0 = *(const float4*)(&zxT[c][0]);   // broadcast
    const float4 a1 = *(const float4*)(&zxT[c][4]);   // broadcast
    const float za[8] = {a0.x, a0.y, a0.z, a0.w, a1.x, a1.y, a1.z, a1.w};
    #pragma unroll
    for (int r = 0; r < RH_ROWS; ++r) {
      acc[r][0] = fmaf(za[r], bv.x, acc[r][0]);
      acc[r][1] = fmaf(za[r], bv.y, acc[r][1]);
      acc[r][2] = fmaf(za[r], bv.z, acc[r][2]);
      acc[r][3] = fmaf(za[r], bv.w, acc[r][3]);
    }
  }

  // per-row: lane-local min (ascending j) -> wave shfl reduce -> LDS
  #pragma unroll
  for (int r = 0; r < RH_ROWS; ++r) {
    const float sxr = sxs[r];
    float s1 = 3.4e38f;
    int   j1 = 0x7fffffff;
    #pragma unroll
    for (int cc = 0; cc < 4; ++cc) {
      const int j = jbase + cc;
      const float t1 = sxr + ses4[cc];
      const float sv = t1 - 2.0f * acc[r][cc];
      if (sv < s1 || (sv == s1 && j < j1)) { s1 = sv; j1 = j; }
    }
    #pragma unroll
    for (int m = 1; m <= 32; m <<= 1) {
      const float so = __shfl_xor(s1, m, 64);
      const int   jo = __shfl_xor(j1, m, 64);
      if (so < s1 || (so == s1 && jo < j1)) { s1 = so; j1 = jo; }
    }
    if (lane == 0) { redS[r][w] = s1; redI[r][w] = j1; }
  }
  __syncthreads();

  // cross-wave merge (4 quarters, ascending code ranges) + write + loss
  if (tid < RH_ROWS) {
    float bs = redS[tid][0];
    int   bj = redI[tid][0];
    #pragma unroll
    for (int ww = 1; ww < 4; ++ww) {
      const float a1 = redS[tid][ww];
      const int   aj = redI[tid][ww];
      if (a1 < bs || (a1 == bs && aj < bj)) { bs = a1; bj = aj; }
    }
    double lp = 0.0;
    if (i0 + tid < hc) {
      const int n = sn[tid];
      idx_i[n] = bj;
      out_idx_f[n] = (float)bj;
      atomicAdd(&counts[bj], 1);
      lp = (double)bs;                 // bs == sx + se - 2P == ||z-e||^2
    }
    dred[tid] = lp;
  }
  __syncthreads();
  if (tid == 0) {
    double t = 0.0;
    #pragma unroll
    for (int r = 0; r < RH_ROWS; ++r) t += dred[r];
    if (t != 0.0) atomicAdd(loss_sum, t);
  }
}

// gather-only z_q write (out == z_q; straight-through is identity in fwd)
__global__ __launch_bounds__(256) void phase2c_kernel(const float* __restrict__ emb,
                                                      const int* __restrict__ idx_i,
                                                      float* __restrict__ out_zq) {
  __shared__ float els[64 * 257];
  __shared__ int sidx[64];
  const int tid = threadIdx.x;
  const int blk = blockIdx.x, b = blk >> 8, s0 = (blk & 255) << 6;
  if (tid < 64) sidx[tid] = idx_i[b * SPATIAL + s0 + tid];
  __syncthreads();
  {
    const int rr = tid >> 2, p = tid & 3;
    const float* ep = emb + (size_t)sidx[rr] * Dd + p * 64;
    float* dl = els + rr * 257 + p * 64;
    #pragma unroll
    for (int i = 0; i < 64; i += 4) {
      const float4 e4 = *(const float4*)(ep + i);
      dl[i] = e4.x; dl[i + 1] = e4.y; dl[i + 2] = e4.z; dl[i + 3] = e4.w;
    }
  }
  __syncthreads();
  const int s4 = tid & 15, cg = tid >> 4;
  const size_t zb = (size_t)b * (Dd * SPATIAL);
  #pragma unroll 4
  for (int c = cg; c < Dd; c += 16) {
    float4 v;
    v.x = els[(s4 * 4 + 0) * 257 + c];
    v.y = els[(s4 * 4 + 1) * 257 + c];
    v.z = els[(s4 * 4 + 2) * 257 + c];
    v.w = els[(s4 * 4 + 3) * 257 + c];
    *(float4*)(out_zq + zb + (size_t)c * SPATIAL + s0 + s4 * 4) = v;
  }
}

__global__ __launch_bounds__(256) void finalize_kernel(const int* __restrict__ counts,
                                                       const double* __restrict__ loss_sum,
                                                       float* __restrict__ out) {
  const int tid = threadIdx.x;
  double local = 0.0;
  for (int k = tid; k < Kc; k += 256) {
    const double p = (double)counts[k] / (double)NROWS;
    local += p * log(p + 1e-10);
  }
  #pragma unroll
  for (int off = 32; off; off >>= 1) local += __shfl_down(local, off, 64);
  __shared__ double dred[4];
  if ((tid & 63) == 0) dred[tid >> 6] = local;
  __syncthreads();
  if (tid == 0) {
    const double H = dred[0] + dred[1] + dred[2] + dred[3];
    out[PERP_OFF] = (float)exp(-H);
    out[LOSS_OFF] = (float)(0.25 * loss_sum[0] / (double)NELEM);
  }
}

// ===================== OLD (round-3) FALLBACK PATH ==========================

__global__ __launch_bounds__(256) void prep_kernel(const float* __restrict__ emb,
                                                   float* __restrict__ eT,
                                                   float* __restrict__ se) {
  const int j = blockIdx.x, c = threadIdx.x;
  float v = emb[j * Dd + c];
  eT[c * Kc + j] = v;
  double s = (double)v * (double)v;
  #pragma unroll
  for (int off = 32; off; off >>= 1) s += __shfl_down(s, off, 64);
  __shared__ double ws4[4];
  if ((threadIdx.x & 63) == 0) ws4[threadIdx.x >> 6] = s;
  __syncthreads();
  if (threadIdx.x == 0) se[j] = (float)(ws4[0] + ws4[1] + ws4[2] + ws4[3]);
}

__global__ __launch_bounds__(256) void sx_kernel(const float* __restrict__ z,
                                                 float* __restrict__ sx) {
  __shared__ double part[4][64];
  const int tid = threadIdx.x, r = tid & 63, cg = tid >> 6;
  const int blk = blockIdx.x, b = blk >> 8, s0 = (blk & 255) << 6;
  const float* zb = z + (size_t)b * (Dd * SPATIAL);
  double acc = 0.0;
  for (int c = cg * 64; c < cg * 64 + 64; ++c) {
    const float v = zb[(size_t)c * SPATIAL + s0 + r];
    acc += (double)v * (double)v;
  }
  part[cg][r] = acc;
  __syncthreads();
  if (tid < 64)
    sx[b * SPATIAL + s0 + tid] =
        (float)(part[0][tid] + part[1][tid] + part[2][tid] + part[3][tid]);
}

__global__ __launch_bounds__(256) void argmin_kernel(const float* __restrict__ z,
                                                     const float* __restrict__ eT,
                                                     const float* __restrict__ se,
                                                     const float* __restrict__ sx,
                                                     float* __restrict__ out_idx_f,
                                                     int* __restrict__ idx_i,
                                                     int* __restrict__ counts) {
  __shared__ float As[32 * 64];
  __shared__ float Bs[32 * 64];
  __shared__ float ses[Kc];
  __shared__ float sxs[64];
  __shared__ float redS1[64 * 16];
  __shared__ int   redI1[64 * 16];
  const int tid = threadIdx.x, tc = tid & 15, tr = tid >> 4;
  const int blk = blockIdx.x, b = blk >> 8, s0 = (blk & 255) << 6;
  const float* zb = z + (size_t)b * (Dd * SPATIAL);
  #pragma unroll
  for (int i = 0; i < 4; ++i) ses[tid + 256 * i] = se[tid + 256 * i];
  if (tid < 64) sxs[tid] = sx[b * SPATIAL + s0 + tid];
  float s1[4]; int j1[4];
  #pragma unroll
  for (int r = 0; r < 4; ++r) { s1[r] = 3.4e38f; j1[r] = 0; }
  for (int j0 = 0; j0 < Kc; j0 += 64) {
    float acc[4][4];
    #pragma unroll
    for (int rr = 0; rr < 4; ++rr)
      #pragma unroll
      for (int cc = 0; cc < 4; ++cc) acc[rr][cc] = 0.0f;
    for (int c0 = 0; c0 < Dd; c0 += 32) {
      __syncthreads();
      #pragma unroll
      for (int i = 0; i < 8; ++i) {
        const int e = i * 256 + tid, ci = e >> 6, r = e & 63;
        As[e] = zb[(size_t)(c0 + ci) * SPATIAL + s0 + r];
        Bs[e] = eT[(c0 + ci) * Kc + j0 + r];
      }
      __syncthreads();
      #pragma unroll
      for (int d = 0; d < 32; ++d) {
        const float4 av = *reinterpret_cast<const float4*>(&As[d * 64 + 4 * tr]);
        const float4 bv = *reinterpret_cast<const float4*>(&Bs[d * 64 + 4 * tc]);
        const float aa[4] = {av.x, av.y, av.z, av.w};
        const float bb[4] = {bv.x, bv.y, bv.z, bv.w};
        #pragma unroll
        for (int rr = 0; rr < 4; ++rr)
          #pragma unroll
          for (int cc = 0; cc < 4; ++cc)
            acc[rr][cc] = fmaf(aa[rr], bb[cc], acc[rr][cc]);
      }
    }
    #pragma unroll
    for (int rr = 0; rr < 4; ++rr) {
      const float sxr = sxs[4 * tr + rr];
      #pragma unroll
      for (int cc = 0; cc < 4; ++cc) {
        const int j = j0 + 4 * tc + cc;
        const float t1 = sxr + ses[j];
        const float s = t1 - 2.0f * acc[rr][cc];
        if (s < s1[rr] || (s == s1[rr] && j < j1[rr])) { s1[rr] = s; j1[rr] = j; }
      }
    }
  }
  #pragma unroll
  for (int rr = 0; rr < 4; ++rr) {
    redS1[(4 * tr + rr) * 16 + tc] = s1[rr];
    redI1[(4 * tr + rr) * 16 + tc] = j1[rr];
  }
  __syncthreads();
  if (tid < 64) {
    float bs = redS1[tid * 16];
    int bj = redI1[tid * 16];
    #pragma unroll
    for (int t = 1; t < 16; ++t) {
      const float a1 = redS1[tid * 16 + t];
      const int aj = redI1[tid * 16 + t];
      if (a1 < bs || (a1 == bs && aj < bj)) { bs = a1; bj = aj; }
    }
    const int n = b * SPATIAL + s0 + tid;
    out_idx_f[n] = (float)bj;
    idx_i[n] = bj;
    atomicAdd(&counts[bj], 1);
  }
}

__global__ __launch_bounds__(256) void phase2_kernel(const float* __restrict__ z,
                                                     const float* __restrict__ eT,
                                                     const int* __restrict__ idx_i,
                                                     float* __restrict__ out_zq,
                                                     double* __restrict__ loss_sum) {
  __shared__ int sidx[64];
  __shared__ double dred[4];
  const int tid = threadIdx.x;
  const int blk = blockIdx.x, b = blk >> 8, s0 = (blk & 255) << 6;
  if (tid < 64) sidx[tid] = idx_i[b * SPATIAL + s0 + tid];
  __syncthreads();
  const int s = tid & 63, coff = tid >> 6;
  const size_t zb = (size_t)b * (Dd * SPATIAL);
  const int myidx = sidx[s];
  double lsum = 0.0;
  for (int c = coff; c < Dd; c += 4) {
    const size_t off = zb + (size_t)c * SPATIAL + s0 + s;
    const float zv = z[off];
    const float zq = eT[c * Kc + myidx];
    out_zq[off] = zv + (zq - zv);
    const float d = zv - zq;
    lsum += (double)d * (double)d;
  }
  #pragma unroll
  for (int off = 32; off; off >>= 1) lsum += __shfl_down(lsum, off, 64);
  if ((tid & 63) == 0) dred[tid >> 6] = lsum;
  __syncthreads();
  if (tid == 0) atomicAdd(loss_sum, dred[0] + dred[1] + dred[2] + dred[3]);
}

// ================================ LAUNCH ====================================

extern "C" void kernel_launch(void* const* d_in, const int* in_sizes, int n_in,
                              void* d_out, int out_size, void* d_ws, size_t ws_size,
                              hipStream_t stream) {
  const float* z   = (const float*)d_in[0];
  const float* emb = (const float*)d_in[1];
  float* out = (float*)d_out;
  char* ws = (char*)d_ws;

  // fast-path ws layout
  const size_t OFF_SE   = 8192;
  const size_t OFF_SX   = 12288;
  const size_t OFF_EF   = 274432;
  const size_t OFF_IDX  = 1060864;
  const size_t OFF_ET   = 1585152;   // 1 MB
  const size_t OFF_HARD = 3682304;
  const size_t NEED     = 3944448;

  double* loss_sum = (double*)(ws + 0);
  int*    hardcnt  = (int*)(ws + 8);
  int*    counts   = (int*)(ws + 256);

  hipMemsetAsync(d_ws, 0, 8192, stream);  // loss_sum + hardcnt + counts

  if (ws_size >= NEED) {
    float*    se        = (float*)(ws + OFF_SE);
    float*    sx        = (float*)(ws + OFF_SX);
    _Float16* efp       = (_Float16*)(ws + OFF_EF);
    int*      idx_i     = (int*)(ws + OFF_IDX);
    float*    eT        = (float*)(ws + OFF_ET);
    int*      hardlist  = (int*)(ws + OFF_HARD);

    prep2_kernel<<<Kc, 256, 0, stream>>>(emb, efp, eT, se);
    prefilter2_kernel<<<2048, 512, 0, stream>>>(z, efp, se, sx,
                                                out + IDX_OFF, idx_i, counts,
                                                hardcnt, hardlist, loss_sum);
    resolve_hard_kernel<<<NROWS / RH_ROWS, 256, 0, stream>>>(
        z, eT, se, sx, hardcnt, hardlist, out + IDX_OFF, idx_i, counts, loss_sum);
    phase2c_kernel<<<1024, 256, 0, stream>>>(emb, idx_i, out);
    finalize_kernel<<<1, 256, 0, stream>>>(counts, loss_sum, out);
  } else {
    // round-3 proven fallback
    float* eT    = (float*)(ws + 8192);
    float* se    = (float*)(ws + 8192 + 1048576);
    float* sx    = (float*)(ws + 8192 + 1048576 + 4096);
    int*   idx_i = (int*)(ws + 8192 + 1048576 + 4096 + 262144);

    prep_kernel<<<Kc, 256, 0, stream>>>(emb, eT, se);
    sx_kernel<<<1024, 256, 0, stream>>>(z, sx);
    argmin_kernel<<<1024, 256, 0, stream>>>(z, eT, se, sx, out + IDX_OFF, idx_i, counts);
    phase2_kernel<<<1024, 256, 0, stream>>>(z, eT, idx_i, out, loss_sum);
    finalize_kernel<<<1, 256, 0, stream>>>(counts, loss_sum, out);
  }
}

// Round 11
// 287.024 us; speedup vs baseline: 1.4126x; 1.0105x over previous
//
// v8: prefilter launch_bounds (512,4)->(512,2) — lifts the empirical 64-VGPR
// cap that was spilling ~55MB/dispatch (same signature as round 1). No other
// changes vs the verified v7b.
#include <hip/hip_runtime.h>

// Problem constants
#define Dd 256           // embedding dim (== channel count C)
#define Kc 1024          // num codes
#define SPATIAL 16384    // 16*32*32
#define NROWS 65536      // 4 * SPATIAL
#define NELEM 16777216   // 4*256*16384
#define LOSS_OFF 16777216
#define IDX_OFF  16777217
#define PERP_OFF (16777217 + 65536)
#define MARGIN 3.5e-4f
#define RH_ROWS 8        // hard rows per resolve block

typedef _Float16 f16x8 __attribute__((ext_vector_type(8)));
typedef float f32x4 __attribute__((ext_vector_type(4)));

// ============================ FAST PATH =====================================

// emb -> efp (packed MFMA-B fragment layout, f16, scaled by 1024) + eT + se.
__global__ __launch_bounds__(256) void prep2_kernel(const float* __restrict__ emb,
                                                    _Float16* __restrict__ efp,
                                                    float* __restrict__ eT,
                                                    float* __restrict__ se) {
  const int j = blockIdx.x, c = threadIdx.x;
  float v = emb[j * Dd + c];
  const int ct2 = j >> 4, l15 = j & 15;
  const int kk = c >> 5, q = (c >> 3) & 3, e = c & 7;
  efp[((size_t)(ct2 * 8 + kk) * 64 + q * 16 + l15) * 8 + e] = (_Float16)(v * 1024.0f);
  eT[c * Kc + j] = v;
  double s = (double)v * (double)v;
  #pragma unroll
  for (int off = 32; off; off >>= 1) s += __shfl_down(s, off, 64);
  __shared__ double ws4[4];
  if ((threadIdx.x & 63) == 0) ws4[threadIdx.x >> 6] = s;
  __syncthreads();
  if (threadIdx.x == 0) se[j] = (float)(ws4[0] + ws4[1] + ws4[2] + ws4[3]);
}

// Fused: z transpose->f16 + sx + MFMA scores with IN-REGISTER (min1,col,min2)
// tracking + inline easy-row resolve + ordered hard-list append.
// NOTE: (512,2) not (512,4) — measured twice that (512,4) resolves to a
// 64-VGPR budget on this toolchain (r1: 76MB spill, r10: 55MB spill). The
// ~115-reg working set (Afrag 64 + track 24 + temps) needs the 128 cap.
__global__ __launch_bounds__(512, 2) void prefilter2_kernel(const float* __restrict__ z,
                                                            const _Float16* __restrict__ efp,
                                                            const float* __restrict__ se,
                                                            float* __restrict__ sx,
                                                            float* __restrict__ out_idx_f,
                                                            int* __restrict__ idx_i,
                                                            int* __restrict__ counts,
                                                            int* __restrict__ hardcnt,
                                                            int* __restrict__ hardlist,
                                                            double* __restrict__ loss_sum) {
  __shared__ _Float16 As[32 * 272];    // 17408 B transposed z tile (f16)
  __shared__ float sxp[16][32];
  __shared__ float selds[Kc];
  __shared__ float rm1w[8][32];
  __shared__ float rm2w[8][32];
  __shared__ int   rc1w[8][32];

  const int tid = threadIdx.x;
  const int n0 = blockIdx.x * 32;
  const int b = n0 >> 14, s0 = n0 & 16383;
  const float* zb = z + (size_t)b * (Dd * SPATIAL) + s0;

  // stage + transpose + sx partials (512 threads: 16 channels each)
  {
    const int r = tid & 31, cp = tid >> 5;   // cp in 0..15
    float acc = 0.0f;
    #pragma unroll
    for (int c = cp * 16; c < cp * 16 + 16; ++c) {
      const float v = zb[(size_t)c * SPATIAL + r];
      As[r * 272 + c] = (_Float16)v;
      acc = fmaf(v, v, acc);
    }
    sxp[cp][r] = acc;
  }
  selds[tid] = se[tid];
  selds[tid + 512] = se[tid + 512];
  __syncthreads();

  float sxv = 0.0f;            // per-row ||z||^2 (rows tid<32)
  if (tid < 32) {
    float s = 0.0f;
    #pragma unroll
    for (int p = 0; p < 16; ++p) s += sxp[p][tid];
    sxv = s;
    sx[n0 + tid] = s;
  }

  const int w = tid >> 6, lane = tid & 63, q = lane >> 4, l15 = lane & 15;
  const int colbase = w * 128;

  // A fragments -> registers (rows rt*16+l15, k = kk*32 + q*8)
  f16x8 Afrag[2][8];
  #pragma unroll
  for (int rt = 0; rt < 2; ++rt)
    #pragma unroll
    for (int kk = 0; kk < 8; ++kk)
      Afrag[rt][kk] = *(const f16x8*)(&As[(rt * 16 + l15) * 272 + kk * 32 + q * 8]);

  float m1[8], m2[8];
  int   c1[8];
  #pragma unroll
  for (int i = 0; i < 8; ++i) { m1[i] = 3.4e38f; m2[i] = 3.4e38f; c1[i] = 0; }

  #pragma unroll
  for (int ct = 0; ct < 8; ++ct) {
    const _Float16* bp = efp + ((size_t)((w * 8 + ct) * 8) * 64 + lane) * 8;
    f32x4 a0 = {0.f, 0.f, 0.f, 0.f}, a1 = {0.f, 0.f, 0.f, 0.f};
    #pragma unroll
    for (int kk = 0; kk < 8; ++kk) {
      const f16x8 B = *(const f16x8*)(bp + kk * 512);
      a0 = __builtin_amdgcn_mfma_f32_16x16x32_f16(Afrag[0][kk], B, a0, 0, 0, 0);
      a1 = __builtin_amdgcn_mfma_f32_16x16x32_f16(Afrag[1][kk], B, a1, 0, 0, 0);
    }
    const int col = colbase + ct * 16 + l15;
    const float sec = selds[col];
    #pragma unroll
    for (int reg = 0; reg < 4; ++reg) {
      const float sc0 = fmaf(-0.001953125f, a0[reg], sec);  // se - 2P (/1024 scale)
      const float sc1 = fmaf(-0.001953125f, a1[reg], sec);
      m2[reg] = fminf(m2[reg], fmaxf(m1[reg], sc0));
      c1[reg] = (sc0 < m1[reg]) ? col : c1[reg];
      m1[reg] = fminf(m1[reg], sc0);
      m2[4 + reg] = fminf(m2[4 + reg], fmaxf(m1[4 + reg], sc1));
      c1[4 + reg] = (sc1 < m1[4 + reg]) ? col : c1[4 + reg];
      m1[4 + reg] = fminf(m1[4 + reg], sc1);
    }
  }

  // cross-lane merge over l15 (lanes sharing q hold the same rows)
  #pragma unroll
  for (int m = 1; m <= 8; m <<= 1) {
    #pragma unroll
    for (int i = 0; i < 8; ++i) {
      const float om1 = __shfl_xor(m1[i], m, 64);
      const float om2 = __shfl_xor(m2[i], m, 64);
      const int   oc1 = __shfl_xor(c1[i], m, 64);
      m2[i] = fminf(fminf(m2[i], om2), fmaxf(m1[i], om1));
      if (om1 < m1[i]) { m1[i] = om1; c1[i] = oc1; }
    }
  }
  if (l15 == 0) {
    #pragma unroll
    for (int reg = 0; reg < 4; ++reg) {
      rm1w[w][q * 4 + reg] = m1[reg];
      rm2w[w][q * 4 + reg] = m2[reg];
      rc1w[w][q * 4 + reg] = c1[reg];
      rm1w[w][16 + q * 4 + reg] = m1[4 + reg];
      rm2w[w][16 + q * 4 + reg] = m2[4 + reg];
      rc1w[w][16 + q * 4 + reg] = c1[4 + reg];
    }
  }
  __syncthreads();

  // epilogue (first wave): cross-wave merge, easy resolve, hard append, loss
  if (tid < 64) {
    double lp = 0.0;
    int hard = 0;
    const int n = n0 + tid;
    if (tid < 32) {
      float bm1 = rm1w[0][tid], bm2 = rm2w[0][tid];
      int   bc1 = rc1w[0][tid];
      #pragma unroll
      for (int ww = 1; ww < 8; ++ww) {
        const float a1v = rm1w[ww][tid], a2v = rm2w[ww][tid];
        const int   ac = rc1w[ww][tid];
        bm2 = fminf(fminf(bm2, a2v), fmaxf(bm1, a1v));
        if (a1v < bm1) { bm1 = a1v; bc1 = ac; }
      }
      if (bm2 >= bm1 + MARGIN) {
        idx_i[n] = bc1;
        out_idx_f[n] = (float)bc1;
        atomicAdd(&counts[bc1], 1);
        lp = (double)sxv + (double)bm1;   // ||z-e||^2 = sx + (se - 2P)
      } else {
        hard = 1;
      }
    }
    const unsigned long long mask = __ballot(hard);
    const int h = __popcll(mask);
    int base = 0;
    if (tid == 0 && h) base = atomicAdd(hardcnt, h);
    base = __shfl(base, 0, 64);
    if (hard) {
      const int rank = __popcll(mask & ((1ull << tid) - 1ull));
      hardlist[base + rank] = n;
    }
    #pragma unroll
    for (int off = 32; off; off >>= 1) lp += __shfl_down(lp, off, 64);
    if (tid == 0 && lp != 0.0) atomicAdd(loss_sum, lp);
  }
}

// Exact rescore, co-tiled: block = 8 hard rows x 1024 codes; wave w owns code
// quarter [256w, 256w+256) for ALL 8 rows -> 32 FMAs per eT float4 load, 32
// independent chains/lane. z staged once as zxT[c][row] (16B-aligned rows,
// broadcast ds_read_b128 in main loop). Per-code FMA chain ascending c —
// bit-identical scores to verified v4/v6; min-j tie-break at every level.
__global__ __launch_bounds__(256) void resolve_hard_kernel(const float* __restrict__ z,
                                                           const float* __restrict__ eT,
                                                           const float* __restrict__ se,
                                                           const float* __restrict__ sx,
                                                           const int* __restrict__ hardcnt,
                                                           const int* __restrict__ hardlist,
                                                           float* __restrict__ out_idx_f,
                                                           int* __restrict__ idx_i,
                                                           int* __restrict__ counts,
                                                           double* __restrict__ loss_sum) {
  const int hc = *hardcnt;
  const int i0 = blockIdx.x * RH_ROWS;
  if (i0 >= hc) return;
  const int tid = threadIdx.x;

  __shared__ int   sn[RH_ROWS];
  __shared__ float sxs[RH_ROWS];
  __shared__ __align__(16) float zxT[Dd][12];   // [c][row], row-quad 16B aligned
  __shared__ float redS[RH_ROWS][4];
  __shared__ int   redI[RH_ROWS][4];
  __shared__ double dred[RH_ROWS];

  if (tid < RH_ROWS) {
    const int ii = i0 + tid;
    const int n = (ii < hc) ? hardlist[ii] : hardlist[i0];  // pad: dup row
    sn[tid] = n;
    sxs[tid] = sx[n];
  }
  __syncthreads();

  // gather z rows once: row r by 32 threads, 8 channels each
  {
    const int r = tid >> 5, cs = tid & 31;
    const int n = sn[r], b = n >> 14, s = n & 16383;
    const float* zr = z + (size_t)b * (Dd * SPATIAL) + s;
    #pragma unroll
    for (int k = 0; k < 8; ++k)
      zxT[cs + 32 * k][r] = zr[(size_t)(cs + 32 * k) * SPATIAL];
  }
  __syncthreads();

  const int w = tid >> 6, lane = tid & 63;
  const int jbase = w * 256 + 4 * lane;        // this lane's 4 codes
  const float4 se4v = *(const float4*)(se + jbase);
  const float ses4[4] = {se4v.x, se4v.y, se4v.z, se4v.w};

  float acc[RH_ROWS][4];
  #pragma unroll
  for (int r = 0; r < RH_ROWS; ++r)
    #pragma unroll
    for (int cc = 0; cc < 4; ++cc) acc[r][cc] = 0.f;

  const float* ecol = eT + jbase;
  #pragma unroll 4
  for (int c = 0; c < Dd; ++c) {
    const float4 bv = *(const float4*)(ecol + (size_t)c * Kc);
    const float4 a0 = *(const float4*)(&zxT[c][0]);   // broadcast
    const float4 a1 = *(const float4*)(&zxT[c][4]);   // broadcast
    const float za[8] = {a0.x, a0.y, a0.z, a0.w, a1.x, a1.y, a1.z, a1.w};
    #pragma unroll
    for (int r = 0; r < RH_ROWS; ++r) {
      acc[r][0] = fmaf(za[r], bv.x, acc[r][0]);
      acc[r][1] = fmaf(za[r], bv.y, acc[r][1]);
      acc[r][2] = fmaf(za[r], bv.z, acc[r][2]);
      acc[r][3] = fmaf(za[r], bv.w, acc[r][3]);
    }
  }

  // per-row: lane-local min (ascending j) -> wave shfl reduce -> LDS
  #pragma unroll
  for (int r = 0; r < RH_ROWS; ++r) {
    const float sxr = sxs[r];
    float s1 = 3.4e38f;
    int   j1 = 0x7fffffff;
    #pragma unroll
    for (int cc = 0; cc < 4; ++cc) {
      const int j = jbase + cc;
      const float t1 = sxr + ses4[cc];
      const float sv = t1 - 2.0f * acc[r][cc];
      if (sv < s1 || (sv == s1 && j < j1)) { s1 = sv; j1 = j; }
    }
    #pragma unroll
    for (int m = 1; m <= 32; m <<= 1) {
      const float so = __shfl_xor(s1, m, 64);
      const int   jo = __shfl_xor(j1, m, 64);
      if (so < s1 || (so == s1 && jo < j1)) { s1 = so; j1 = jo; }
    }
    if (lane == 0) { redS[r][w] = s1; redI[r][w] = j1; }
  }
  __syncthreads();

  // cross-wave merge (4 quarters, ascending code ranges) + write + loss
  if (tid < RH_ROWS) {
    float bs = redS[tid][0];
    int   bj = redI[tid][0];
    #pragma unroll
    for (int ww = 1; ww < 4; ++ww) {
      const float a1 = redS[tid][ww];
      const int   aj = redI[tid][ww];
      if (a1 < bs || (a1 == bs && aj < bj)) { bs = a1; bj = aj; }
    }
    double lp = 0.0;
    if (i0 + tid < hc) {
      const int n = sn[tid];
      idx_i[n] = bj;
      out_idx_f[n] = (float)bj;
      atomicAdd(&counts[bj], 1);
      lp = (double)bs;                 // bs == sx + se - 2P == ||z-e||^2
    }
    dred[tid] = lp;
  }
  __syncthreads();
  if (tid == 0) {
    double t = 0.0;
    #pragma unroll
    for (int r = 0; r < RH_ROWS; ++r) t += dred[r];
    if (t != 0.0) atomicAdd(loss_sum, t);
  }
}

// gather-only z_q write (out == z_q; straight-through is identity in fwd)
__global__ __launch_bounds__(256) void phase2c_kernel(const float* __restrict__ emb,
                                                      const int* __restrict__ idx_i,
                                                      float* __restrict__ out_zq) {
  __shared__ float els[64 * 257];
  __shared__ int sidx[64];
  const int tid = threadIdx.x;
  const int blk = blockIdx.x, b = blk >> 8, s0 = (blk & 255) << 6;
  if (tid < 64) sidx[tid] = idx_i[b * SPATIAL + s0 + tid];
  __syncthreads();
  {
    const int rr = tid >> 2, p = tid & 3;
    const float* ep = emb + (size_t)sidx[rr] * Dd + p * 64;
    float* dl = els + rr * 257 + p * 64;
    #pragma unroll
    for (int i = 0; i < 64; i += 4) {
      const float4 e4 = *(const float4*)(ep + i);
      dl[i] = e4.x; dl[i + 1] = e4.y; dl[i + 2] = e4.z; dl[i + 3] = e4.w;
    }
  }
  __syncthreads();
  const int s4 = tid & 15, cg = tid >> 4;
  const size_t zb = (size_t)b * (Dd * SPATIAL);
  #pragma unroll 4
  for (int c = cg; c < Dd; c += 16) {
    float4 v;
    v.x = els[(s4 * 4 + 0) * 257 + c];
    v.y = els[(s4 * 4 + 1) * 257 + c];
    v.z = els[(s4 * 4 + 2) * 257 + c];
    v.w = els[(s4 * 4 + 3) * 257 + c];
    *(float4*)(out_zq + zb + (size_t)c * SPATIAL + s0 + s4 * 4) = v;
  }
}

__global__ __launch_bounds__(256) void finalize_kernel(const int* __restrict__ counts,
                                                       const double* __restrict__ loss_sum,
                                                       float* __restrict__ out) {
  const int tid = threadIdx.x;
  double local = 0.0;
  for (int k = tid; k < Kc; k += 256) {
    const double p = (double)counts[k] / (double)NROWS;
    local += p * log(p + 1e-10);
  }
  #pragma unroll
  for (int off = 32; off; off >>= 1) local += __shfl_down(local, off, 64);
  __shared__ double dred[4];
  if ((tid & 63) == 0) dred[tid >> 6] = local;
  __syncthreads();
  if (tid == 0) {
    const double H = dred[0] + dred[1] + dred[2] + dred[3];
    out[PERP_OFF] = (float)exp(-H);
    out[LOSS_OFF] = (float)(0.25 * loss_sum[0] / (double)NELEM);
  }
}

// ===================== OLD (round-3) FALLBACK PATH ==========================

__global__ __launch_bounds__(256) void prep_kernel(const float* __restrict__ emb,
                                                   float* __restrict__ eT,
                                                   float* __restrict__ se) {
  const int j = blockIdx.x, c = threadIdx.x;
  float v = emb[j * Dd + c];
  eT[c * Kc + j] = v;
  double s = (double)v * (double)v;
  #pragma unroll
  for (int off = 32; off; off >>= 1) s += __shfl_down(s, off, 64);
  __shared__ double ws4[4];
  if ((threadIdx.x & 63) == 0) ws4[threadIdx.x >> 6] = s;
  __syncthreads();
  if (threadIdx.x == 0) se[j] = (float)(ws4[0] + ws4[1] + ws4[2] + ws4[3]);
}

__global__ __launch_bounds__(256) void sx_kernel(const float* __restrict__ z,
                                                 float* __restrict__ sx) {
  __shared__ double part[4][64];
  const int tid = threadIdx.x, r = tid & 63, cg = tid >> 6;
  const int blk = blockIdx.x, b = blk >> 8, s0 = (blk & 255) << 6;
  const float* zb = z + (size_t)b * (Dd * SPATIAL);
  double acc = 0.0;
  for (int c = cg * 64; c < cg * 64 + 64; ++c) {
    const float v = zb[(size_t)c * SPATIAL + s0 + r];
    acc += (double)v * (double)v;
  }
  part[cg][r] = acc;
  __syncthreads();
  if (tid < 64)
    sx[b * SPATIAL + s0 + tid] =
        (float)(part[0][tid] + part[1][tid] + part[2][tid] + part[3][tid]);
}

__global__ __launch_bounds__(256) void argmin_kernel(const float* __restrict__ z,
                                                     const float* __restrict__ eT,
                                                     const float* __restrict__ se,
                                                     const float* __restrict__ sx,
                                                     float* __restrict__ out_idx_f,
                                                     int* __restrict__ idx_i,
                                                     int* __restrict__ counts) {
  __shared__ float As[32 * 64];
  __shared__ float Bs[32 * 64];
  __shared__ float ses[Kc];
  __shared__ float sxs[64];
  __shared__ float redS1[64 * 16];
  __shared__ int   redI1[64 * 16];
  const int tid = threadIdx.x, tc = tid & 15, tr = tid >> 4;
  const int blk = blockIdx.x, b = blk >> 8, s0 = (blk & 255) << 6;
  const float* zb = z + (size_t)b * (Dd * SPATIAL);
  #pragma unroll
  for (int i = 0; i < 4; ++i) ses[tid + 256 * i] = se[tid + 256 * i];
  if (tid < 64) sxs[tid] = sx[b * SPATIAL + s0 + tid];
  float s1[4]; int j1[4];
  #pragma unroll
  for (int r = 0; r < 4; ++r) { s1[r] = 3.4e38f; j1[r] = 0; }
  for (int j0 = 0; j0 < Kc; j0 += 64) {
    float acc[4][4];
    #pragma unroll
    for (int rr = 0; rr < 4; ++rr)
      #pragma unroll
      for (int cc = 0; cc < 4; ++cc) acc[rr][cc] = 0.0f;
    for (int c0 = 0; c0 < Dd; c0 += 32) {
      __syncthreads();
      #pragma unroll
      for (int i = 0; i < 8; ++i) {
        const int e = i * 256 + tid, ci = e >> 6, r = e & 63;
        As[e] = zb[(size_t)(c0 + ci) * SPATIAL + s0 + r];
        Bs[e] = eT[(c0 + ci) * Kc + j0 + r];
      }
      __syncthreads();
      #pragma unroll
      for (int d = 0; d < 32; ++d) {
        const float4 av = *reinterpret_cast<const float4*>(&As[d * 64 + 4 * tr]);
        const float4 bv = *reinterpret_cast<const float4*>(&Bs[d * 64 + 4 * tc]);
        const float aa[4] = {av.x, av.y, av.z, av.w};
        const float bb[4] = {bv.x, bv.y, bv.z, bv.w};
        #pragma unroll
        for (int rr = 0; rr < 4; ++rr)
          #pragma unroll
          for (int cc = 0; cc < 4; ++cc)
            acc[rr][cc] = fmaf(aa[rr], bb[cc], acc[rr][cc]);
      }
    }
    #pragma unroll
    for (int rr = 0; rr < 4; ++rr) {
      const float sxr = sxs[4 * tr + rr];
      #pragma unroll
      for (int cc = 0; cc < 4; ++cc) {
        const int j = j0 + 4 * tc + cc;
        const float t1 = sxr + ses[j];
        const float s = t1 - 2.0f * acc[rr][cc];
        if (s < s1[rr] || (s == s1[rr] && j < j1[rr])) { s1[rr] = s; j1[rr] = j; }
      }
    }
  }
  #pragma unroll
  for (int rr = 0; rr < 4; ++rr) {
    redS1[(4 * tr + rr) * 16 + tc] = s1[rr];
    redI1[(4 * tr + rr) * 16 + tc] = j1[rr];
  }
  __syncthreads();
  if (tid < 64) {
    float bs = redS1[tid * 16];
    int bj = redI1[tid * 16];
    #pragma unroll
    for (int t = 1; t < 16; ++t) {
      const float a1 = redS1[tid * 16 + t];
      const int aj = redI1[tid * 16 + t];
      if (a1 < bs || (a1 == bs && aj < bj)) { bs = a1; bj = aj; }
    }
    const int n = b * SPATIAL + s0 + tid;
    out_idx_f[n] = (float)bj;
    idx_i[n] = bj;
    atomicAdd(&counts[bj], 1);
  }
}

__global__ __launch_bounds__(256) void phase2_kernel(const float* __restrict__ z,
                                                     const float* __restrict__ eT,
                                                     const int* __restrict__ idx_i,
                                                     float* __restrict__ out_zq,
                                                     double* __restrict__ loss_sum) {
  __shared__ int sidx[64];
  __shared__ double dred[4];
  const int tid = threadIdx.x;
  const int blk = blockIdx.x, b = blk >> 8, s0 = (blk & 255) << 6;
  if (tid < 64) sidx[tid] = idx_i[b * SPATIAL + s0 + tid];
  __syncthreads();
  const int s = tid & 63, coff = tid >> 6;
  const size_t zb = (size_t)b * (Dd * SPATIAL);
  const int myidx = sidx[s];
  double lsum = 0.0;
  for (int c = coff; c < Dd; c += 4) {
    const size_t off = zb + (size_t)c * SPATIAL + s0 + s;
    const float zv = z[off];
    const float zq = eT[c * Kc + myidx];
    out_zq[off] = zv + (zq - zv);
    const float d = zv - zq;
    lsum += (double)d * (double)d;
  }
  #pragma unroll
  for (int off = 32; off; off >>= 1) lsum += __shfl_down(lsum, off, 64);
  if ((tid & 63) == 0) dred[tid >> 6] = lsum;
  __syncthreads();
  if (tid == 0) atomicAdd(loss_sum, dred[0] + dred[1] + dred[2] + dred[3]);
}

// ================================ LAUNCH ====================================

extern "C" void kernel_launch(void* const* d_in, const int* in_sizes, int n_in,
                              void* d_out, int out_size, void* d_ws, size_t ws_size,
                              hipStream_t stream) {
  const float* z   = (const float*)d_in[0];
  const float* emb = (const float*)d_in[1];
  float* out = (float*)d_out;
  char* ws = (char*)d_ws;

  // fast-path ws layout
  const size_t OFF_SE   = 8192;
  const size_t OFF_SX   = 12288;
  const size_t OFF_EF   = 274432;
  const size_t OFF_IDX  = 1060864;
  const size_t OFF_ET   = 1585152;   // 1 MB
  const size_t OFF_HARD = 3682304;
  const size_t NEED     = 3944448;

  double* loss_sum = (double*)(ws + 0);
  int*    hardcnt  = (int*)(ws + 8);
  int*    counts   = (int*)(ws + 256);

  hipMemsetAsync(d_ws, 0, 8192, stream);  // loss_sum + hardcnt + counts

  if (ws_size >= NEED) {
    float*    se        = (float*)(ws + OFF_SE);
    float*    sx        = (float*)(ws + OFF_SX);
    _Float16* efp       = (_Float16*)(ws + OFF_EF);
    int*      idx_i     = (int*)(ws + OFF_IDX);
    float*    eT        = (float*)(ws + OFF_ET);
    int*      hardlist  = (int*)(ws + OFF_HARD);

    prep2_kernel<<<Kc, 256, 0, stream>>>(emb, efp, eT, se);
    prefilter2_kernel<<<2048, 512, 0, stream>>>(z, efp, se, sx,
                                                out + IDX_OFF, idx_i, counts,
                                                hardcnt, hardlist, loss_sum);
    resolve_hard_kernel<<<NROWS / RH_ROWS, 256, 0, stream>>>(
        z, eT, se, sx, hardcnt, hardlist, out + IDX_OFF, idx_i, counts, loss_sum);
    phase2c_kernel<<<1024, 256, 0, stream>>>(emb, idx_i, out);
    finalize_kernel<<<1, 256, 0, stream>>>(counts, loss_sum, out);
  } else {
    // round-3 proven fallback
    float* eT    = (float*)(ws + 8192);
    float* se    = (float*)(ws + 8192 + 1048576);
    float* sx    = (float*)(ws + 8192 + 1048576 + 4096);
    int*   idx_i = (int*)(ws + 8192 + 1048576 + 4096 + 262144);

    prep_kernel<<<Kc, 256, 0, stream>>>(emb, eT, se);
    sx_kernel<<<1024, 256, 0, stream>>>(z, sx);
    argmin_kernel<<<1024, 256, 0, stream>>>(z, eT, se, sx, out + IDX_OFF, idx_i, counts);
    phase2_kernel<<<1024, 256, 0, stream>>>(z, eT, idx_i, out, loss_sum);
    finalize_kernel<<<1, 256, 0, stream>>>(counts, loss_sum, out);
  }
}

// Round 12
// 266.726 us; speedup vs baseline: 1.5201x; 1.0761x over previous
//
// v9: prefilter re-tiled 64 rows x 4 waves x 256 cols (256 threads) — halves
// B traffic (1GB->0.5GB L2), doubles MFMA per B-load; track fits registers
// by design. Same verified score algebra. Rest identical to v8.
#include <hip/hip_runtime.h>

// Problem constants
#define Dd 256           // embedding dim (== channel count C)
#define Kc 1024          // num codes
#define SPATIAL 16384    // 16*32*32
#define NROWS 65536      // 4 * SPATIAL
#define NELEM 16777216   // 4*256*16384
#define LOSS_OFF 16777216
#define IDX_OFF  16777217
#define PERP_OFF (16777217 + 65536)
#define MARGIN 3.5e-4f
#define RH_ROWS 8        // hard rows per resolve block
#define ASTRIDE 264      // f16 elems; 528B row stride (16B aligned; 2-way bank alias = free)

typedef _Float16 f16x8 __attribute__((ext_vector_type(8)));
typedef float f32x4 __attribute__((ext_vector_type(4)));

// ============================ FAST PATH =====================================

// emb -> efp (packed MFMA-B fragment layout, f16, scaled by 1024) + eT + se.
__global__ __launch_bounds__(256) void prep2_kernel(const float* __restrict__ emb,
                                                    _Float16* __restrict__ efp,
                                                    float* __restrict__ eT,
                                                    float* __restrict__ se) {
  const int j = blockIdx.x, c = threadIdx.x;
  float v = emb[j * Dd + c];
  const int ct2 = j >> 4, l15 = j & 15;
  const int kk = c >> 5, q = (c >> 3) & 3, e = c & 7;
  efp[((size_t)(ct2 * 8 + kk) * 64 + q * 16 + l15) * 8 + e] = (_Float16)(v * 1024.0f);
  eT[c * Kc + j] = v;
  double s = (double)v * (double)v;
  #pragma unroll
  for (int off = 32; off; off >>= 1) s += __shfl_down(s, off, 64);
  __shared__ double ws4[4];
  if ((threadIdx.x & 63) == 0) ws4[threadIdx.x >> 6] = s;
  __syncthreads();
  if (threadIdx.x == 0) se[j] = (float)(ws4[0] + ws4[1] + ws4[2] + ws4[3]);
}

// Fused: z transpose->f16 + sx + MFMA scores with IN-REGISTER (min1,col,min2)
// tracking + inline easy-row resolve + ordered hard-list append.
// 64 rows x 1024 cols per block; 4 waves; wave w owns cols [w*256, w*256+256).
// Per-lane slot sl = rt*4+reg <-> row rt*16 + q*4 + reg, col = colbase+ct*16+l15.
__global__ __launch_bounds__(256) void prefilter2_kernel(const float* __restrict__ z,
                                                         const _Float16* __restrict__ efp,
                                                         const float* __restrict__ se,
                                                         float* __restrict__ sx,
                                                         float* __restrict__ out_idx_f,
                                                         int* __restrict__ idx_i,
                                                         int* __restrict__ counts,
                                                         int* __restrict__ hardcnt,
                                                         int* __restrict__ hardlist,
                                                         double* __restrict__ loss_sum) {
  __shared__ _Float16 As[64 * ASTRIDE];   // 33792 B transposed z tile (f16)
  __shared__ float sxp[4][64];
  __shared__ float selds[Kc];
  __shared__ float rm1w[4][64];
  __shared__ float rm2w[4][64];
  __shared__ int   rc1w[4][64];

  const int tid = threadIdx.x;
  const int n0 = blockIdx.x * 64;
  const int b = n0 >> 14, s0 = n0 & 16383;
  const float* zb = z + (size_t)b * (Dd * SPATIAL) + s0;

  // stage + transpose + sx partials (256 threads: 64 channels each)
  {
    const int r = tid & 63, cp = tid >> 6;   // cp in 0..3
    float acc = 0.0f;
    #pragma unroll
    for (int c = cp * 64; c < cp * 64 + 64; ++c) {
      const float v = zb[(size_t)c * SPATIAL + r];
      As[r * ASTRIDE + c] = (_Float16)v;
      acc = fmaf(v, v, acc);
    }
    sxp[cp][r] = acc;
  }
  #pragma unroll
  for (int i = 0; i < 4; ++i) selds[tid + 256 * i] = se[tid + 256 * i];
  __syncthreads();

  float sxv = 0.0f;            // per-row ||z||^2 (rows tid<64)
  if (tid < 64) {
    float s = sxp[0][tid] + sxp[1][tid] + sxp[2][tid] + sxp[3][tid];
    sxv = s;
    sx[n0 + tid] = s;
  }

  const int w = tid >> 6, lane = tid & 63, q = lane >> 4, l15 = lane & 15;
  const int colbase = w * 256;

  float m1[16], m2[16];
  int   c1[16];
  #pragma unroll
  for (int i = 0; i < 16; ++i) { m1[i] = 3.4e38f; m2[i] = 3.4e38f; c1[i] = 0; }

  #pragma unroll 2
  for (int ct = 0; ct < 16; ++ct) {
    // coalesced packed-B: 1KB contiguous per (ct,kk) across the wave
    const _Float16* bp = efp + ((size_t)((w * 16 + ct) * 8) * 64 + lane) * 8;
    f16x8 B[8];
    #pragma unroll
    for (int kk = 0; kk < 8; ++kk) B[kk] = *(const f16x8*)(bp + kk * 512);
    const int col = colbase + ct * 16 + l15;
    const float sec = selds[col];
    #pragma unroll
    for (int rt = 0; rt < 4; ++rt) {
      f32x4 a = {0.f, 0.f, 0.f, 0.f};
      #pragma unroll
      for (int kk = 0; kk < 8; ++kk) {
        const f16x8 A = *(const f16x8*)(&As[(rt * 16 + l15) * ASTRIDE + kk * 32 + q * 8]);
        a = __builtin_amdgcn_mfma_f32_16x16x32_f16(A, B[kk], a, 0, 0, 0);
      }
      #pragma unroll
      for (int reg = 0; reg < 4; ++reg) {
        const float sc = fmaf(-0.001953125f, a[reg], sec);  // se - 2P (/1024 scale)
        const int sl = rt * 4 + reg;
        m2[sl] = fminf(m2[sl], fmaxf(m1[sl], sc));
        c1[sl] = (sc < m1[sl]) ? col : c1[sl];
        m1[sl] = fminf(m1[sl], sc);
      }
    }
  }

  // cross-lane merge over l15 (lanes sharing q hold the same rows)
  #pragma unroll
  for (int m = 1; m <= 8; m <<= 1) {
    #pragma unroll
    for (int i = 0; i < 16; ++i) {
      const float om1 = __shfl_xor(m1[i], m, 64);
      const float om2 = __shfl_xor(m2[i], m, 64);
      const int   oc1 = __shfl_xor(c1[i], m, 64);
      m2[i] = fminf(fminf(m2[i], om2), fmaxf(m1[i], om1));
      if (om1 < m1[i]) { m1[i] = om1; c1[i] = oc1; }
    }
  }
  if (l15 == 0) {
    #pragma unroll
    for (int rt = 0; rt < 4; ++rt)
      #pragma unroll
      for (int reg = 0; reg < 4; ++reg) {
        const int row = rt * 16 + q * 4 + reg;
        rm1w[w][row] = m1[rt * 4 + reg];
        rm2w[w][row] = m2[rt * 4 + reg];
        rc1w[w][row] = c1[rt * 4 + reg];
      }
  }
  __syncthreads();

  // epilogue (first wave): cross-wave merge, easy resolve, hard append, loss
  if (tid < 64) {
    double lp = 0.0;
    int hard = 0;
    const int n = n0 + tid;
    {
      float bm1 = rm1w[0][tid], bm2 = rm2w[0][tid];
      int   bc1 = rc1w[0][tid];
      #pragma unroll
      for (int ww = 1; ww < 4; ++ww) {
        const float a1v = rm1w[ww][tid], a2v = rm2w[ww][tid];
        const int   ac = rc1w[ww][tid];
        bm2 = fminf(fminf(bm2, a2v), fmaxf(bm1, a1v));
        if (a1v < bm1) { bm1 = a1v; bc1 = ac; }
      }
      if (bm2 >= bm1 + MARGIN) {
        idx_i[n] = bc1;
        out_idx_f[n] = (float)bc1;
        atomicAdd(&counts[bc1], 1);
        lp = (double)sxv + (double)bm1;   // ||z-e||^2 = sx + (se - 2P)
      } else {
        hard = 1;
      }
    }
    const unsigned long long mask = __ballot(hard);
    const int h = __popcll(mask);
    int base = 0;
    if (tid == 0 && h) base = atomicAdd(hardcnt, h);
    base = __shfl(base, 0, 64);
    if (hard) {
      const int rank = __popcll(mask & ((1ull << tid) - 1ull));
      hardlist[base + rank] = n;
    }
    #pragma unroll
    for (int off = 32; off; off >>= 1) lp += __shfl_down(lp, off, 64);
    if (tid == 0 && lp != 0.0) atomicAdd(loss_sum, lp);
  }
}

// Exact rescore, co-tiled: block = 8 hard rows x 1024 codes; wave w owns code
// quarter [256w, 256w+256) for ALL 8 rows -> 32 FMAs per eT float4 load, 32
// independent chains/lane. z staged once as zxT[c][row] (16B-aligned rows,
// broadcast ds_read_b128 in main loop). Per-code FMA chain ascending c —
// bit-identical scores to verified v4/v6; min-j tie-break at every level.
__global__ __launch_bounds__(256) void resolve_hard_kernel(const float* __restrict__ z,
                                                           const float* __restrict__ eT,
                                                           const float* __restrict__ se,
                                                           const float* __restrict__ sx,
                                                           const int* __restrict__ hardcnt,
                                                           const int* __restrict__ hardlist,
                                                           float* __restrict__ out_idx_f,
                                                           int* __restrict__ idx_i,
                                                           int* __restrict__ counts,
                                                           double* __restrict__ loss_sum) {
  const int hc = *hardcnt;
  const int i0 = blockIdx.x * RH_ROWS;
  if (i0 >= hc) return;
  const int tid = threadIdx.x;

  __shared__ int   sn[RH_ROWS];
  __shared__ float sxs[RH_ROWS];
  __shared__ __align__(16) float zxT[Dd][12];   // [c][row], row-quad 16B aligned
  __shared__ float redS[RH_ROWS][4];
  __shared__ int   redI[RH_ROWS][4];
  __shared__ double dred[RH_ROWS];

  if (tid < RH_ROWS) {
    const int ii = i0 + tid;
    const int n = (ii < hc) ? hardlist[ii] : hardlist[i0];  // pad: dup row
    sn[tid] = n;
    sxs[tid] = sx[n];
  }
  __syncthreads();

  // gather z rows once: row r by 32 threads, 8 channels each
  {
    const int r = tid >> 5, cs = tid & 31;
    const int n = sn[r], b = n >> 14, s = n & 16383;
    const float* zr = z + (size_t)b * (Dd * SPATIAL) + s;
    #pragma unroll
    for (int k = 0; k < 8; ++k)
      zxT[cs + 32 * k][r] = zr[(size_t)(cs + 32 * k) * SPATIAL];
  }
  __syncthreads();

  const int w = tid >> 6, lane = tid & 63;
  const int jbase = w * 256 + 4 * lane;        // this lane's 4 codes
  const float4 se4v = *(const float4*)(se + jbase);
  const float ses4[4] = {se4v.x, se4v.y, se4v.z, se4v.w};

  float acc[RH_ROWS][4];
  #pragma unroll
  for (int r = 0; r < RH_ROWS; ++r)
    #pragma unroll
    for (int cc = 0; cc < 4; ++cc) acc[r][cc] = 0.f;

  const float* ecol = eT + jbase;
  #pragma unroll 4
  for (int c = 0; c < Dd; ++c) {
    const float4 bv = *(const float4*)(ecol + (size_t)c * Kc);
    const float4 a0 = *(const float4*)(&zxT[c][0]);   // broadcast
    const float4 a1 = *(const float4*)(&zxT[c][4]);   // broadcast
    const float za[8] = {a0.x, a0.y, a0.z, a0.w, a1.x, a1.y, a1.z, a1.w};
    #pragma unroll
    for (int r = 0; r < RH_ROWS; ++r) {
      acc[r][0] = fmaf(za[r], bv.x, acc[r][0]);
      acc[r][1] = fmaf(za[r], bv.y, acc[r][1]);
      acc[r][2] = fmaf(za[r], bv.z, acc[r][2]);
      acc[r][3] = fmaf(za[r], bv.w, acc[r][3]);
    }
  }

  // per-row: lane-local min (ascending j) -> wave shfl reduce -> LDS
  #pragma unroll
  for (int r = 0; r < RH_ROWS; ++r) {
    const float sxr = sxs[r];
    float s1 = 3.4e38f;
    int   j1 = 0x7fffffff;
    #pragma unroll
    for (int cc = 0; cc < 4; ++cc) {
      const int j = jbase + cc;
      const float t1 = sxr + ses4[cc];
      const float sv = t1 - 2.0f * acc[r][cc];
      if (sv < s1 || (sv == s1 && j < j1)) { s1 = sv; j1 = j; }
    }
    #pragma unroll
    for (int m = 1; m <= 32; m <<= 1) {
      const float so = __shfl_xor(s1, m, 64);
      const int   jo = __shfl_xor(j1, m, 64);
      if (so < s1 || (so == s1 && jo < j1)) { s1 = so; j1 = jo; }
    }
    if (lane == 0) { redS[r][w] = s1; redI[r][w] = j1; }
  }
  __syncthreads();

  // cross-wave merge (4 quarters, ascending code ranges) + write + loss
  if (tid < RH_ROWS) {
    float bs = redS[tid][0];
    int   bj = redI[tid][0];
    #pragma unroll
    for (int ww = 1; ww < 4; ++ww) {
      const float a1 = redS[tid][ww];
      const int   aj = redI[tid][ww];
      if (a1 < bs || (a1 == bs && aj < bj)) { bs = a1; bj = aj; }
    }
    double lp = 0.0;
    if (i0 + tid < hc) {
      const int n = sn[tid];
      idx_i[n] = bj;
      out_idx_f[n] = (float)bj;
      atomicAdd(&counts[bj], 1);
      lp = (double)bs;                 // bs == sx + se - 2P == ||z-e||^2
    }
    dred[tid] = lp;
  }
  __syncthreads();
  if (tid == 0) {
    double t = 0.0;
    #pragma unroll
    for (int r = 0; r < RH_ROWS; ++r) t += dred[r];
    if (t != 0.0) atomicAdd(loss_sum, t);
  }
}

// gather-only z_q write (out == z_q; straight-through is identity in fwd)
__global__ __launch_bounds__(256) void phase2c_kernel(const float* __restrict__ emb,
                                                      const int* __restrict__ idx_i,
                                                      float* __restrict__ out_zq) {
  __shared__ float els[64 * 257];
  __shared__ int sidx[64];
  const int tid = threadIdx.x;
  const int blk = blockIdx.x, b = blk >> 8, s0 = (blk & 255) << 6;
  if (tid < 64) sidx[tid] = idx_i[b * SPATIAL + s0 + tid];
  __syncthreads();
  {
    const int rr = tid >> 2, p = tid & 3;
    const float* ep = emb + (size_t)sidx[rr] * Dd + p * 64;
    float* dl = els + rr * 257 + p * 64;
    #pragma unroll
    for (int i = 0; i < 64; i += 4) {
      const float4 e4 = *(const float4*)(ep + i);
      dl[i] = e4.x; dl[i + 1] = e4.y; dl[i + 2] = e4.z; dl[i + 3] = e4.w;
    }
  }
  __syncthreads();
  const int s4 = tid & 15, cg = tid >> 4;
  const size_t zb = (size_t)b * (Dd * SPATIAL);
  #pragma unroll 4
  for (int c = cg; c < Dd; c += 16) {
    float4 v;
    v.x = els[(s4 * 4 + 0) * 257 + c];
    v.y = els[(s4 * 4 + 1) * 257 + c];
    v.z = els[(s4 * 4 + 2) * 257 + c];
    v.w = els[(s4 * 4 + 3) * 257 + c];
    *(float4*)(out_zq + zb + (size_t)c * SPATIAL + s0 + s4 * 4) = v;
  }
}

__global__ __launch_bounds__(256) void finalize_kernel(const int* __restrict__ counts,
                                                       const double* __restrict__ loss_sum,
                                                       float* __restrict__ out) {
  const int tid = threadIdx.x;
  double local = 0.0;
  for (int k = tid; k < Kc; k += 256) {
    const double p = (double)counts[k] / (double)NROWS;
    local += p * log(p + 1e-10);
  }
  #pragma unroll
  for (int off = 32; off; off >>= 1) local += __shfl_down(local, off, 64);
  __shared__ double dred[4];
  if ((tid & 63) == 0) dred[tid >> 6] = local;
  __syncthreads();
  if (tid == 0) {
    const double H = dred[0] + dred[1] + dred[2] + dred[3];
    out[PERP_OFF] = (float)exp(-H);
    out[LOSS_OFF] = (float)(0.25 * loss_sum[0] / (double)NELEM);
  }
}

// ===================== OLD (round-3) FALLBACK PATH ==========================

__global__ __launch_bounds__(256) void prep_kernel(const float* __restrict__ emb,
                                                   float* __restrict__ eT,
                                                   float* __restrict__ se) {
  const int j = blockIdx.x, c = threadIdx.x;
  float v = emb[j * Dd + c];
  eT[c * Kc + j] = v;
  double s = (double)v * (double)v;
  #pragma unroll
  for (int off = 32; off; off >>= 1) s += __shfl_down(s, off, 64);
  __shared__ double ws4[4];
  if ((threadIdx.x & 63) == 0) ws4[threadIdx.x >> 6] = s;
  __syncthreads();
  if (threadIdx.x == 0) se[j] = (float)(ws4[0] + ws4[1] + ws4[2] + ws4[3]);
}

__global__ __launch_bounds__(256) void sx_kernel(const float* __restrict__ z,
                                                 float* __restrict__ sx) {
  __shared__ double part[4][64];
  const int tid = threadIdx.x, r = tid & 63, cg = tid >> 6;
  const int blk = blockIdx.x, b = blk >> 8, s0 = (blk & 255) << 6;
  const float* zb = z + (size_t)b * (Dd * SPATIAL);
  double acc = 0.0;
  for (int c = cg * 64; c < cg * 64 + 64; ++c) {
    const float v = zb[(size_t)c * SPATIAL + s0 + r];
    acc += (double)v * (double)v;
  }
  part[cg][r] = acc;
  __syncthreads();
  if (tid < 64)
    sx[b * SPATIAL + s0 + tid] =
        (float)(part[0][tid] + part[1][tid] + part[2][tid] + part[3][tid]);
}

__global__ __launch_bounds__(256) void argmin_kernel(const float* __restrict__ z,
                                                     const float* __restrict__ eT,
                                                     const float* __restrict__ se,
                                                     const float* __restrict__ sx,
                                                     float* __restrict__ out_idx_f,
                                                     int* __restrict__ idx_i,
                                                     int* __restrict__ counts) {
  __shared__ float As[32 * 64];
  __shared__ float Bs[32 * 64];
  __shared__ float ses[Kc];
  __shared__ float sxs[64];
  __shared__ float redS1[64 * 16];
  __shared__ int   redI1[64 * 16];
  const int tid = threadIdx.x, tc = tid & 15, tr = tid >> 4;
  const int blk = blockIdx.x, b = blk >> 8, s0 = (blk & 255) << 6;
  const float* zb = z + (size_t)b * (Dd * SPATIAL);
  #pragma unroll
  for (int i = 0; i < 4; ++i) ses[tid + 256 * i] = se[tid + 256 * i];
  if (tid < 64) sxs[tid] = sx[b * SPATIAL + s0 + tid];
  float s1[4]; int j1[4];
  #pragma unroll
  for (int r = 0; r < 4; ++r) { s1[r] = 3.4e38f; j1[r] = 0; }
  for (int j0 = 0; j0 < Kc; j0 += 64) {
    float acc[4][4];
    #pragma unroll
    for (int rr = 0; rr < 4; ++rr)
      #pragma unroll
      for (int cc = 0; cc < 4; ++cc) acc[rr][cc] = 0.0f;
    for (int c0 = 0; c0 < Dd; c0 += 32) {
      __syncthreads();
      #pragma unroll
      for (int i = 0; i < 8; ++i) {
        const int e = i * 256 + tid, ci = e >> 6, r = e & 63;
        As[e] = zb[(size_t)(c0 + ci) * SPATIAL + s0 + r];
        Bs[e] = eT[(c0 + ci) * Kc + j0 + r];
      }
      __syncthreads();
      #pragma unroll
      for (int d = 0; d < 32; ++d) {
        const float4 av = *reinterpret_cast<const float4*>(&As[d * 64 + 4 * tr]);
        const float4 bv = *reinterpret_cast<const float4*>(&Bs[d * 64 + 4 * tc]);
        const float aa[4] = {av.x, av.y, av.z, av.w};
        const float bb[4] = {bv.x, bv.y, bv.z, bv.w};
        #pragma unroll
        for (int rr = 0; rr < 4; ++rr)
          #pragma unroll
          for (int cc = 0; cc < 4; ++cc)
            acc[rr][cc] = fmaf(aa[rr], bb[cc], acc[rr][cc]);
      }
    }
    #pragma unroll
    for (int rr = 0; rr < 4; ++rr) {
      const float sxr = sxs[4 * tr + rr];
      #pragma unroll
      for (int cc = 0; cc < 4; ++cc) {
        const int j = j0 + 4 * tc + cc;
        const float t1 = sxr + ses[j];
        const float s = t1 - 2.0f * acc[rr][cc];
        if (s < s1[rr] || (s == s1[rr] && j < j1[rr])) { s1[rr] = s; j1[rr] = j; }
      }
    }
  }
  #pragma unroll
  for (int rr = 0; rr < 4; ++rr) {
    redS1[(4 * tr + rr) * 16 + tc] = s1[rr];
    redI1[(4 * tr + rr) * 16 + tc] = j1[rr];
  }
  __syncthreads();
  if (tid < 64) {
    float bs = redS1[tid * 16];
    int bj = redI1[tid * 16];
    #pragma unroll
    for (int t = 1; t < 16; ++t) {
      const float a1 = redS1[tid * 16 + t];
      const int aj = redI1[tid * 16 + t];
      if (a1 < bs || (a1 == bs && aj < bj)) { bs = a1; bj = aj; }
    }
    const int n = b * SPATIAL + s0 + tid;
    out_idx_f[n] = (float)bj;
    idx_i[n] = bj;
    atomicAdd(&counts[bj], 1);
  }
}

__global__ __launch_bounds__(256) void phase2_kernel(const float* __restrict__ z,
                                                     const float* __restrict__ eT,
                                                     const int* __restrict__ idx_i,
                                                     float* __restrict__ out_zq,
                                                     double* __restrict__ loss_sum) {
  __shared__ int sidx[64];
  __shared__ double dred[4];
  const int tid = threadIdx.x;
  const int blk = blockIdx.x, b = blk >> 8, s0 = (blk & 255) << 6;
  if (tid < 64) sidx[tid] = idx_i[b * SPATIAL + s0 + tid];
  __syncthreads();
  const int s = tid & 63, coff = tid >> 6;
  const size_t zb = (size_t)b * (Dd * SPATIAL);
  const int myidx = sidx[s];
  double lsum = 0.0;
  for (int c = coff; c < Dd; c += 4) {
    const size_t off = zb + (size_t)c * SPATIAL + s0 + s;
    const float zv = z[off];
    const float zq = eT[c * Kc + myidx];
    out_zq[off] = zv + (zq - zv);
    const float d = zv - zq;
    lsum += (double)d * (double)d;
  }
  #pragma unroll
  for (int off = 32; off; off >>= 1) lsum += __shfl_down(lsum, off, 64);
  if ((tid & 63) == 0) dred[tid >> 6] = lsum;
  __syncthreads();
  if (tid == 0) atomicAdd(loss_sum, dred[0] + dred[1] + dred[2] + dred[3]);
}

// ================================ LAUNCH ====================================

extern "C" void kernel_launch(void* const* d_in, const int* in_sizes, int n_in,
                              void* d_out, int out_size, void* d_ws, size_t ws_size,
                              hipStream_t stream) {
  const float* z   = (const float*)d_in[0];
  const float* emb = (const float*)d_in[1];
  float* out = (float*)d_out;
  char* ws = (char*)d_ws;

  // fast-path ws layout
  const size_t OFF_SE   = 8192;
  const size_t OFF_SX   = 12288;
  const size_t OFF_EF   = 274432;
  const size_t OFF_IDX  = 1060864;
  const size_t OFF_ET   = 1585152;   // 1 MB
  const size_t OFF_HARD = 3682304;
  const size_t NEED     = 3944448;

  double* loss_sum = (double*)(ws + 0);
  int*    hardcnt  = (int*)(ws + 8);
  int*    counts   = (int*)(ws + 256);

  hipMemsetAsync(d_ws, 0, 8192, stream);  // loss_sum + hardcnt + counts

  if (ws_size >= NEED) {
    float*    se        = (float*)(ws + OFF_SE);
    float*    sx        = (float*)(ws + OFF_SX);
    _Float16* efp       = (_Float16*)(ws + OFF_EF);
    int*      idx_i     = (int*)(ws + OFF_IDX);
    float*    eT        = (float*)(ws + OFF_ET);
    int*      hardlist  = (int*)(ws + OFF_HARD);

    prep2_kernel<<<Kc, 256, 0, stream>>>(emb, efp, eT, se);
    prefilter2_kernel<<<NROWS / 64, 256, 0, stream>>>(z, efp, se, sx,
                                                      out + IDX_OFF, idx_i, counts,
                                                      hardcnt, hardlist, loss_sum);
    resolve_hard_kernel<<<NROWS / RH_ROWS, 256, 0, stream>>>(
        z, eT, se, sx, hardcnt, hardlist, out + IDX_OFF, idx_i, counts, loss_sum);
    phase2c_kernel<<<1024, 256, 0, stream>>>(emb, idx_i, out);
    finalize_kernel<<<1, 256, 0, stream>>>(counts, loss_sum, out);
  } else {
    // round-3 proven fallback
    float* eT    = (float*)(ws + 8192);
    float* se    = (float*)(ws + 8192 + 1048576);
    float* sx    = (float*)(ws + 8192 + 1048576 + 4096);
    int*   idx_i = (int*)(ws + 8192 + 1048576 + 4096 + 262144);

    prep_kernel<<<Kc, 256, 0, stream>>>(emb, eT, se);
    sx_kernel<<<1024, 256, 0, stream>>>(z, sx);
    argmin_kernel<<<1024, 256, 0, stream>>>(z, eT, se, sx, out + IDX_OFF, idx_i, counts);
    phase2_kernel<<<1024, 256, 0, stream>>>(z, eT, idx_i, out, loss_sum);
    finalize_kernel<<<1, 256, 0, stream>>>(counts, loss_sum, out);
  }
}